// Round 11
// baseline (588.890 us; speedup 1.0000x reference)
//
#include <hip/hip_runtime.h>

typedef short s8v __attribute__((ext_vector_type(8)));
typedef float f32x4 __attribute__((ext_vector_type(4)));
typedef unsigned short u16;

__device__ __forceinline__ float bf2f(u16 h){
  union { unsigned u; float f; } v; v.u = ((unsigned)h) << 16; return v.f;
}
__device__ __forceinline__ u16 f2bf(float f){
  union { float f; unsigned u; } v; v.f = f;
  unsigned u = v.u;
  return (u16)((u + 0x7fffu + ((u >> 16) & 1u)) >> 16);
}
#define MFMA(a,b,c) __builtin_amdgcn_mfma_f32_16x16x32_bf16((a),(b),(c),0,0,0)

#define WREDUCE64(s) { s += __shfl_xor(s,1); s += __shfl_xor(s,2); s += __shfl_xor(s,4); \
                       s += __shfl_xor(s,8); s += __shfl_xor(s,16); s += __shfl_xor(s,32); }
#define QREDUCE16(s) { s += __shfl_xor(s,1); s += __shfl_xor(s,2); s += __shfl_xor(s,4); s += __shfl_xor(s,8); }

// 16-value butterfly within 16-lane quads: lane c (0..15) ends with sum-over-quad of val[c]
__device__ __forceinline__ float quad_butterfly16(float* val, int c){
  float v8[8], v4[4], v2[2];
  #pragma unroll
  for(int t=0;t<8;t++){
    float sent = (c&1) ? val[2*t] : val[2*t+1];
    float got = __shfl_xor(sent, 1);
    v8[t] = ((c&1) ? val[2*t+1] : val[2*t]) + got;
  }
  #pragma unroll
  for(int t=0;t<4;t++){
    float sent = ((c>>1)&1) ? v8[2*t] : v8[2*t+1];
    float got = __shfl_xor(sent, 2);
    v4[t] = (((c>>1)&1) ? v8[2*t+1] : v8[2*t]) + got;
  }
  #pragma unroll
  for(int t=0;t<2;t++){
    float sent = ((c>>2)&1) ? v4[2*t] : v4[2*t+1];
    float got = __shfl_xor(sent, 4);
    v2[t] = (((c>>2)&1) ? v4[2*t+1] : v4[2*t]) + got;
  }
  float sent = ((c>>3)&1) ? v2[0] : v2[1];
  float got = __shfl_xor(sent, 8);
  return (((c>>3)&1) ? v2[1] : v2[0]) + got;
}

// ---------------- ONE-SHOT prep: convert + all weight transposes (contiguous dst regions) ----------------
__global__ __launch_bounds__(256) void k_prep(const float* ele, const float* W_embed, const float* W_edge,
    const float* Wq, const float* Wk, const float* Wv, const float* Wr1, const float* Wo,
    const float* W1, const float* W2, const float* W_feat, const float* hW1, const float* hW2,
    u16* dst){
  int idx = blockIdx.x*256 + threadIdx.x;
  if(idx >= 405248) return;
  u16 v;
  if(idx < 3840){                    // ele convert
    v = f2bf(ele[idx]);
  } else if(idx < 5888){             // WembT: R=32,C=64,Rpad=32
    int l = idx - 3840;
    int cI = l >> 5, rI = l & 31;
    v = f2bf(W_embed[rI*64 + cI]);
  } else if(idx < 16128){            // WedgeT: R=137,C=64,Rpad=160
    int l = idx - 5888;
    int cI = l / 160, rI = l - cI*160;
    v = (rI < 137) ? f2bf(W_edge[rI*64 + cI]) : (u16)0;
  } else if(idx < 139008){           // Wq,Wk,Wv,Wr1,Wo: 5 x 6 x 64x64
    int l = idx - 16128;
    int which = l / 24576;
    int rem = l - which*24576;
    const float* src = (which==0)?Wq:(which==1)?Wk:(which==2)?Wv:(which==3)?Wr1:Wo;
    int b = rem >> 12;
    int r2 = rem & 4095;
    int cI = r2 >> 6, rI = r2 & 63;
    v = f2bf(src[b*4096 + rI*64 + cI]);
  } else if(idx < 237312){           // W1T: B=6,R=64,C=256,Rpad=64
    int l = idx - 139008;
    int b = l / 16384;
    int rem = l - b*16384;
    int cI = rem >> 6, rI = rem & 63;
    v = f2bf(W1[b*16384 + rI*256 + cI]);
  } else if(idx < 335616){           // W2T: B=6,R=256,C=64,Rpad=256
    int l = idx - 237312;
    int b = l / 16384;
    int rem = l - b*16384;
    int cI = rem >> 8, rI = rem & 255;
    v = f2bf(W2[b*16384 + rI*64 + cI]);
  } else if(idx < 368384){           // WfT: R=64,C=512,Rpad=64
    int l = idx - 335616;
    int cI = l >> 6, rI = l & 63;
    v = f2bf(W_feat[rI*512 + cI]);
  } else if(idx < 401152){           // hW1T: R=512,C=64,Rpad=512
    int l = idx - 368384;
    int cI = l >> 9, rI = l & 511;
    v = f2bf(hW1[rI*64 + cI]);
  } else {                           // hW2T: R=64,C=64
    int l = idx - 401152;
    int cI = l >> 6, rI = l & 63;
    v = f2bf(hW2[rI*64 + cI]);
  }
  dst[idx] = v;
}

// ---------------- CSR build ----------------
__global__ __launch_bounds__(256) void k_count(const int* dstI, int* deg, int E){
  int tid = blockIdx.x*256 + threadIdx.x;
  if(tid < E) atomicAdd(&deg[dstI[tid]], 1);
}
__global__ __launch_bounds__(1024) void k_scan(const int* deg, int* rowptr, int* cursor, int N){
  __shared__ int wsum[17];
  int tid = threadIdx.x;
  int per = (N + 1023) >> 10;
  int base = tid * per;
  int s = 0;
  for(int i=0;i<per;i++){ int idx = base+i; if(idx < N) s += deg[idx]; }
  int lane = tid & 63, wid = tid >> 6;
  int inc = s;
  for(int d=1; d<64; d<<=1){
    int t = __shfl_up(inc, d);
    if(lane >= d) inc += t;
  }
  if(lane == 63) wsum[wid+1] = inc;
  if(tid == 0) wsum[0] = 0;
  __syncthreads();
  if(tid == 0){ for(int w=1; w<=16; w++) wsum[w] += wsum[w-1]; }
  __syncthreads();
  int run = inc - s + wsum[wid];
  for(int i=0;i<per;i++){
    int idx = base + i;
    if(idx < N){ rowptr[idx] = run; cursor[idx] = run; run += deg[idx]; }
  }
  if(tid == 1023) rowptr[N] = wsum[16];
}
__global__ __launch_bounds__(256) void k_scatter(const int* dstI, int* cursor, int* csr, int E){
  int tid = blockIdx.x*256 + threadIdx.x;
  if(tid < E){
    int p = atomicAdd(&cursor[dstI[tid]], 1);
    csr[p] = tid;
  }
}

// ---------------- e = [nf_src, nf_dst, sh, rbf] @ W_edge, CSR order, TWO tiles per wave ----------------
// Output staged in wave-private LDS, flushed with coalesced 16B stores.
__global__ __launch_bounds__(256) void k_edge_embed(const int* csr, const int* srcI, const int* dstI,
    const int* atom, const u16* ele, const float* evec, const u16* Bt,
    u16* ebf, float* r2, int* src2, int* dst2, int E){
  __shared__ u16 stage[4][32*64];
  int widL = threadIdx.x >> 6;
  int wave = (blockIdx.x*256 + threadIdx.x) >> 6;
  int lane = threadIdx.x & 63;
  int base0 = wave*32; if(base0 >= E) return;
  int c = lane & 15, q = lane >> 4;
  u16* ST = stage[widL];
  s8v a[2][5];
  #pragma unroll
  for(int t=0;t<2;t++){
    int row0 = base0 + t*16;
    int p = row0 + c;
    int e = csr[p];
    int sn = srcI[e], dn = dstI[e];
    float vx = evec[(size_t)e*3+0];
    float vy = evec[(size_t)e*3+1];
    float vz = evec[(size_t)e*3+2];
    float r = sqrtf(vx*vx + vy*vy + vz*vz);
    if(q == 0){ r2[p] = r; src2[p] = sn; dst2[p] = dn; }
    float inv = 1.f/(r + 1e-12f);
    // u = edge_vec[:, [1,2,0]] / r -> x=v1, y=v2, z=v0
    float x = vy*inv, y = vz*inv, z = vx*inv;
    const float s3 = 1.7320508075688772f, s15 = 3.872983346207417f;
    const float s5h = 1.118033988749895f, s15h = 1.9364916731037085f;
    float sh[9];
    sh[0] = 1.f; sh[1] = s3*x; sh[2] = s3*y; sh[3] = s3*z;
    sh[4] = s15*x*y; sh[5] = s15*y*z; sh[6] = s5h*(3.f*z*z - 1.f);
    sh[7] = s15*x*z; sh[8] = s15h*(x*x - y*y);
    a[t][0] = *reinterpret_cast<const s8v*>(ele + (size_t)atom[sn]*32 + q*8);
    a[t][1] = *reinterpret_cast<const s8v*>(ele + (size_t)atom[dn]*32 + q*8);
    #pragma unroll
    for(int j=0;j<8;j++){
      int col = 64 + q*8 + j;
      u16 v;
      if(q == 0)            v = f2bf(sh[j]);
      else if(col < 73)     v = f2bf(sh[8]);
      else { float d = r - (10.f/63.f)*(float)(col-73); v = f2bf(__expf(-81.92f*d*d)); }
      a[t][2][j] = (short)v;
    }
    #pragma unroll
    for(int j=0;j<8;j++){
      float d = r - (10.f/63.f)*(float)(23 + q*8 + j);
      a[t][3][j] = (short)f2bf(__expf(-81.92f*d*d));
    }
    #pragma unroll
    for(int j=0;j<8;j++){
      int col = 128 + q*8 + j;
      u16 v = 0;
      if(col < 137){ float d = r - (10.f/63.f)*(float)(col-73); v = f2bf(__expf(-81.92f*d*d)); }
      a[t][4][j] = (short)v;
    }
  }
  #pragma unroll
  for(int ct=0; ct<4; ct++){
    s8v b[5];
    #pragma unroll
    for(int kc=0; kc<5; kc++)
      b[kc] = *reinterpret_cast<const s8v*>(Bt + (ct*16+c)*160 + kc*32 + q*8);
    #pragma unroll
    for(int t=0;t<2;t++){
      f32x4 acc = {0.f,0.f,0.f,0.f};
      #pragma unroll
      for(int kc=0; kc<5; kc++) acc = MFMA(a[t][kc], b[kc], acc);
      #pragma unroll
      for(int r_=0;r_<4;r_++) ST[(t*16+q*4+r_)*64 + ct*16 + c] = f2bf(acc[r_]);
    }
  }
  // coalesced flush: 32x64 u16 tile = 256 x 16B; 64 lanes x 4 iters
  #pragma unroll
  for(int k=0;k<4;k++){
    int i = k*64 + lane;
    *reinterpret_cast<float4*>(ebf + (size_t)base0*64 + (size_t)i*8) =
        *reinterpret_cast<const float4*>(ST + i*8);
  }
}

// ---------------- one-shot: radial TABLE over r-grid [0,10], 4096 intervals; layer = blockIdx.y ----------------
#define RG 4096
#define RGROWS 4112
__global__ __launch_bounds__(256) void k_radtab(const u16* Wr1T, const float* Wr2, float* radtab){
  int wave = (blockIdx.x*256 + threadIdx.x) >> 6;
  int lane = threadIdx.x & 63;
  int row0 = wave*16; if(row0 >= RGROWS) return;
  int l = blockIdx.y;
  int c = lane & 15, q = lane >> 4;
  float re = (10.f/RG)*(float)(row0 + c);
  s8v r0, r1;
  #pragma unroll
  for(int j=0;j<8;j++){
    float d0 = re - (10.f/63.f)*(float)(q*8+j);
    float d1 = re - (10.f/63.f)*(float)(32+q*8+j);
    r0[j] = (short)f2bf(__expf(-81.92f*d0*d0));
    r1[j] = (short)f2bf(__expf(-81.92f*d1*d1));
  }
  {
    const u16* W1l = Wr1T + l*4096;
    const float4* wr2v = reinterpret_cast<const float4*>(Wr2 + l*256);
    float val[16];
    #pragma unroll
    for(int i=0;i<16;i++) val[i] = 0.f;
    #pragma unroll
    for(int ct=0; ct<4; ct++){
      s8v bw0 = *reinterpret_cast<const s8v*>(W1l + (ct*16+c)*64 + q*8);
      s8v bw1 = *reinterpret_cast<const s8v*>(W1l + (ct*16+c)*64 + 32 + q*8);
      f32x4 hacc = {0.f,0.f,0.f,0.f};
      hacc = MFMA(r0, bw0, hacc); hacc = MFMA(r1, bw1, hacc);
      float4 w2 = wr2v[ct*16 + c];
      #pragma unroll
      for(int r=0;r<4;r++){
        float y = hacc[r];
        float sv = y / (1.f + __expf(-y));
        val[r*4+0] += sv * w2.x;
        val[r*4+1] += sv * w2.y;
        val[r*4+2] += sv * w2.z;
        val[r*4+3] += sv * w2.w;
      }
    }
    float fin = quad_butterfly16(val, c);
    int row = row0 + q*4 + (c>>2);
    if(row <= RG)
      radtab[(size_t)l*RGROWS*4 + (size_t)row0*4 + lane] = fin;
  }
}

// ---------------- pre: x = ele[atom]@Wemb; h0 = LN(x); Q0 = h0@Wq0 (Qt layout) ----------------
__global__ __launch_bounds__(256) void k_pre(const int* atom, const u16* ele, const u16* WembT,
    const u16* WqT0, float* xb, u16* hbf, float* Qt, int M){
  __shared__ u16 ldsH[4][16*72];
  int widL = threadIdx.x >> 6;
  int wave = (blockIdx.x*256 + threadIdx.x) >> 6;
  int lane = threadIdx.x & 63;
  int row0 = wave*16; if(row0 >= M) return;
  int c = lane & 15, q = lane >> 4;
  u16* LH = ldsH[widL];
  int at = atom[row0 + c];
  s8v a = *reinterpret_cast<const s8v*>(ele + (size_t)at*32 + q*8);
  float nx[4][4];
  #pragma unroll
  for(int ct=0; ct<4; ct++){
    s8v b = *reinterpret_cast<const s8v*>(WembT + (ct*16+c)*32 + q*8);
    f32x4 acc = {0.f,0.f,0.f,0.f};
    acc = MFMA(a, b, acc);
    #pragma unroll
    for(int r=0;r<4;r++){
      xb[(size_t)(row0+q*4+r)*64 + ct*16 + c] = acc[r];
      nx[ct][r] = acc[r];
    }
  }
  #pragma unroll
  for(int r=0;r<4;r++){
    float s = nx[0][r]+nx[1][r]+nx[2][r]+nx[3][r];
    QREDUCE16(s);
    float m = s*(1.f/64.f);
    float vv = 0.f;
    #pragma unroll
    for(int ct=0;ct<4;ct++){ float d = nx[ct][r]-m; vv += d*d; }
    QREDUCE16(vv);
    float rs = rsqrtf(vv*(1.f/64.f) + 1e-6f);
    #pragma unroll
    for(int ct=0;ct<4;ct++){
      u16 hb = f2bf((nx[ct][r]-m)*rs);
      hbf[(size_t)(row0+q*4+r)*64 + ct*16 + c] = hb;
      LH[(q*4+r)*72 + ct*16 + c] = hb;
    }
  }
  s8v h0 = *reinterpret_cast<const s8v*>(LH + c*72 + q*8);
  s8v h1 = *reinterpret_cast<const s8v*>(LH + c*72 + 32 + q*8);
  #pragma unroll
  for(int ct=0; ct<4; ct++){
    s8v b0 = *reinterpret_cast<const s8v*>(WqT0 + (ct*16+c)*64 + q*8);
    s8v b1 = *reinterpret_cast<const s8v*>(WqT0 + (ct*16+c)*64 + 32 + q*8);
    f32x4 acc = {0.f,0.f,0.f,0.f};
    acc = MFMA(h0, b0, acc);
    acc = MFMA(h1, b1, acc);
    #pragma unroll
    for(int r=0;r<4;r++) Qt[(size_t)(row0+q*4+r)*64 + c*4 + ct] = acc[r];
  }
}

// ---------------- LAYER (fused krad + mega): grid N/16, 4 waves ----------------
// Edge phase (wave-independent, no barriers): ex for block's own edges -> exb (global, L1-hot),
//   Q read from LDS tile (all edge dsts are in-block). K=(h+e)@Wk via MFMA linearity.
// Then scan (per-head weighted sums) + Wv/Wo/LN/FFN/LN/Qproj node phases.
__global__ __launch_bounds__(256,4) void k_layer(
    const int* rowptr, const int* src2, const int* dst2,
    const u16* hbf_in, const u16* ebf, const float* Qt_in,
    const float* r2, const float* radtab,
    const u16* WkT, const u16* WvT, const u16* WoT, float* x,
    const u16* W1T, const u16* W2T, const u16* WqTn,
    float* Qt_out, u16* hbf_out, u16* xbf, float* exb,
    int writex, int haveQ, int M){
  __shared__ char LB[40192];
  float* QL  = (float*)LB;            // edge phase only (dead before LA written)
  u16*   LA  = (u16*)LB;              // [0,9216) 4 head planes 16*72
  u16*   LA2 = (u16*)(LB+9216);
  u16*   LH  = (u16*)(LB+11520);
  u16*   LT  = (u16*)(LB+13824);
  float* LP  = (float*)(LB+22272);
  float* LSUM= (float*)(LB+39680);
  float* LSSQ= (float*)(LB+39936);
  int w = threadIdx.x >> 6;
  int lane = threadIdx.x & 63;
  int row0 = blockIdx.x * 16; if(row0 >= M) return;
  int c = lane & 15, q = lane >> 4;

  // ---- load Q tile for block's 16 nodes (16x64 f32) ----
  *reinterpret_cast<float4*>(QL + threadIdx.x*4) =
      *reinterpret_cast<const float4*>(Qt_in + (size_t)row0*64 + threadIdx.x*4);
  __syncthreads();

  int e0 = rowptr[row0];
  int e1 = rowptr[row0+16];

  // ---- edge phase: per-wave independent slices of 32 edges ----
  const float4* QLV = reinterpret_cast<const float4*>(QL);
  for(int base0 = e0 + w*32; base0 < e1; base0 += 128){
    s8v h0[2], h1[2], ee0[2], ee1[2];
    #pragma unroll
    for(int t=0;t<2;t++){
      int p = min(base0 + t*16 + c, e1-1);
      int sr = src2[p];
      h0[t] = *reinterpret_cast<const s8v*>(hbf_in + (size_t)sr*64 + q*8);
      h1[t] = *reinterpret_cast<const s8v*>(hbf_in + (size_t)sr*64 + 32 + q*8);
      ee0[t] = *reinterpret_cast<const s8v*>(ebf + (size_t)p*64 + q*8);
      ee1[t] = *reinterpret_cast<const s8v*>(ebf + (size_t)p*64 + 32 + q*8);
    }
    float4 qv[2][4];
    #pragma unroll
    for(int t=0;t<2;t++)
      #pragma unroll
      for(int r=0;r<4;r++){
        int pr = min(base0 + t*16 + q*4 + r, e1-1);
        int dr = dst2[pr] - row0;
        qv[t][r] = QLV[dr*16 + c];
      }
    float val[2][16];
    #pragma unroll
    for(int t=0;t<2;t++)
      #pragma unroll
      for(int i=0;i<16;i++) val[t][i] = 0.f;
    #pragma unroll
    for(int ct=0; ct<4; ct++){
      s8v bk0 = *reinterpret_cast<const s8v*>(WkT + (ct*16+c)*64 + q*8);
      s8v bk1 = *reinterpret_cast<const s8v*>(WkT + (ct*16+c)*64 + 32 + q*8);
      #pragma unroll
      for(int t=0;t<2;t++){
        f32x4 kacc = {0.f,0.f,0.f,0.f};
        kacc = MFMA(h0[t], bk0, kacc);
        kacc = MFMA(h1[t], bk1, kacc);
        kacc = MFMA(ee0[t], bk0, kacc);
        kacc = MFMA(ee1[t], bk1, kacc);
        #pragma unroll
        for(int r=0;r<4;r++){
          float qc = (ct==0)?qv[t][r].x:(ct==1)?qv[t][r].y:(ct==2)?qv[t][r].z:qv[t][r].w;
          val[t][r*4+ct] += 0.25f * kacc[r] * qc;
        }
      }
    }
    #pragma unroll
    for(int t=0;t<2;t++){
      float qk = quad_butterfly16(val[t], c);   // lane c: (r=c>>2, h=c&3)
      int rowg = base0 + t*16 + q*4 + (c>>2);
      int rowc = min(rowg, e1-1);
      float re = r2[rowc];
      float tt = re * ((float)RG/10.f);
      tt = fminf(fmaxf(tt, 0.f), (float)RG - 0.0001f);
      int i0 = (int)tt;
      float fr = tt - (float)i0;
      int h = c & 3;
      float lo = radtab[(size_t)i0*4 + h];
      float hi = radtab[(size_t)(i0+1)*4 + h];
      float logit = qk + lo + (hi - lo)*fr;
      if(rowg < e1)
        exb[(size_t)rowg*4 + h] = (re < 10.f) ? __expf(logit) : 0.f;
    }
  }
  __syncthreads();   // block's exb writes visible (same CU); QL dead

  // ---- scan phase: per-wave, per-HEAD weighted-sum of (h_src+e) rows for 4 nodes -> LA[h] ----
  {
    int ep = lane >> 4, cc = lane & 15;
    #pragma unroll
    for(int j=0;j<4;j++){
      int n = row0 + w*4 + j;
      int s0 = rowptr[n], s1 = rowptr[n+1];
      float acc[4][4];
      #pragma unroll
      for(int h=0;h<4;h++)
        #pragma unroll
        for(int k=0;k<4;k++) acc[h][k] = 0.f;
      float dd0=0.f, dd1=0.f, dd2=0.f, dd3=0.f;
      for(int p = s0 + ep; p < s1; p += 4){
        int sr = src2[p];
        ushort4 hv = *reinterpret_cast<const ushort4*>(hbf_in + (size_t)sr*64 + cc*4);
        ushort4 ev4 = *reinterpret_cast<const ushort4*>(ebf + (size_t)p*64 + cc*4);
        float4 ex = *reinterpret_cast<const float4*>(exb + (size_t)p*4);
        float d0 = bf2f(hv.x)+bf2f(ev4.x), d1 = bf2f(hv.y)+bf2f(ev4.y);
        float d2 = bf2f(hv.z)+bf2f(ev4.z), d3 = bf2f(hv.w)+bf2f(ev4.w);
        dd0 += ex.x; dd1 += ex.y; dd2 += ex.z; dd3 += ex.w;
        acc[0][0] += ex.x*d0; acc[0][1] += ex.x*d1; acc[0][2] += ex.x*d2; acc[0][3] += ex.x*d3;
        acc[1][0] += ex.y*d0; acc[1][1] += ex.y*d1; acc[1][2] += ex.y*d2; acc[1][3] += ex.y*d3;
        acc[2][0] += ex.z*d0; acc[2][1] += ex.z*d1; acc[2][2] += ex.z*d2; acc[2][3] += ex.z*d3;
        acc[3][0] += ex.w*d0; acc[3][1] += ex.w*d1; acc[3][2] += ex.w*d2; acc[3][3] += ex.w*d3;
      }
      dd0 += __shfl_xor(dd0,16); dd0 += __shfl_xor(dd0,32);
      dd1 += __shfl_xor(dd1,16); dd1 += __shfl_xor(dd1,32);
      dd2 += __shfl_xor(dd2,16); dd2 += __shfl_xor(dd2,32);
      dd3 += __shfl_xor(dd3,16); dd3 += __shfl_xor(dd3,32);
      #pragma unroll
      for(int h=0;h<4;h++)
        #pragma unroll
        for(int k=0;k<4;k++){
          acc[h][k] += __shfl_xor(acc[h][k],16);
          acc[h][k] += __shfl_xor(acc[h][k],32);
        }
      if(ep == 0){
        float inv[4];
        inv[0] = 1.f/(dd0 + 1e-9f); inv[1] = 1.f/(dd1 + 1e-9f);
        inv[2] = 1.f/(dd2 + 1e-9f); inv[3] = 1.f/(dd3 + 1e-9f);
        #pragma unroll
        for(int h=0;h<4;h++){
          ushort4 o;
          o.x = f2bf(acc[h][0]*inv[h]); o.y = f2bf(acc[h][1]*inv[h]);
          o.z = f2bf(acc[h][2]*inv[h]); o.w = f2bf(acc[h][3]*inv[h]);
          *reinterpret_cast<ushort4*>(LA + h*1152 + (w*4+j)*72 + cc*4) = o;
        }
      }
    }
  }
  __syncthreads();

  // ---- Phase A0: agg[head w cols] = agg_pre[head w] @ Wv (cols ct=w) -> LA2 ----
  {
    s8v a0 = *reinterpret_cast<const s8v*>(LA + w*1152 + c*72 + q*8);
    s8v a1 = *reinterpret_cast<const s8v*>(LA + w*1152 + c*72 + 32 + q*8);
    s8v b0 = *reinterpret_cast<const s8v*>(WvT + (w*16+c)*64 + q*8);
    s8v b1 = *reinterpret_cast<const s8v*>(WvT + (w*16+c)*64 + 32 + q*8);
    f32x4 acc = {0.f,0.f,0.f,0.f};
    acc = MFMA(a0, b0, acc);
    acc = MFMA(a1, b1, acc);
    #pragma unroll
    for(int r=0;r<4;r++)
      LA2[(q*4+r)*72 + w*16 + c] = f2bf(acc[r]);
  }
  __syncthreads();

  // ---- Phase A: x += agg @ Wo (cols ct=w); cross-wave LN -> LH ----
  float nx[4];
  {
    s8v a0 = *reinterpret_cast<const s8v*>(LA2 + c*72 + q*8);
    s8v a1 = *reinterpret_cast<const s8v*>(LA2 + c*72 + 32 + q*8);
    s8v b0 = *reinterpret_cast<const s8v*>(WoT + (w*16+c)*64 + q*8);
    s8v b1 = *reinterpret_cast<const s8v*>(WoT + (w*16+c)*64 + 32 + q*8);
    f32x4 acc = {0.f,0.f,0.f,0.f};
    acc = MFMA(a0, b0, acc);
    acc = MFMA(a1, b1, acc);
    #pragma unroll
    for(int r=0;r<4;r++){
      size_t idx = (size_t)(row0+q*4+r)*64 + w*16 + c;
      float t = x[idx] + acc[r];
      x[idx] = t;
      nx[r] = t;
    }
  }
  #pragma unroll
  for(int r=0;r<4;r++){
    float s = nx[r];
    QREDUCE16(s);
    if(c == 0) LSUM[w*16 + q*4 + r] = s;
  }
  __syncthreads();
  float m[4];
  #pragma unroll
  for(int r=0;r<4;r++)
    m[r] = (LSUM[q*4+r] + LSUM[16+q*4+r] + LSUM[32+q*4+r] + LSUM[48+q*4+r]) * (1.f/64.f);
  #pragma unroll
  for(int r=0;r<4;r++){
    float d = nx[r]-m[r];
    float vv = d*d;
    QREDUCE16(vv);
    if(c == 0) LSSQ[w*16 + q*4 + r] = vv;
  }
  __syncthreads();
  #pragma unroll
  for(int r=0;r<4;r++){
    float vv = LSSQ[q*4+r] + LSSQ[16+q*4+r] + LSSQ[32+q*4+r] + LSSQ[48+q*4+r];
    float rs = rsqrtf(vv*(1.f/64.f) + 1e-6f);
    LH[(q*4+r)*72 + w*16 + c] = f2bf((nx[r]-m[r])*rs);
  }
  __syncthreads();

  // ---- Phase B: FFN1, cols ct in [4w, 4w+4) -> LT (batched weight loads) ----
  {
    s8v h0 = *reinterpret_cast<const s8v*>(LH + c*72 + q*8);
    s8v h1 = *reinterpret_cast<const s8v*>(LH + c*72 + 32 + q*8);
    s8v wb[4][2];
    #pragma unroll
    for(int t=0;t<4;t++){
      int ct = w*4 + t;
      wb[t][0] = *reinterpret_cast<const s8v*>(W1T + (ct*16+c)*64 + q*8);
      wb[t][1] = *reinterpret_cast<const s8v*>(W1T + (ct*16+c)*64 + 32 + q*8);
    }
    #pragma unroll
    for(int t=0;t<4;t++){
      int ct = w*4 + t;
      f32x4 acc = {0.f,0.f,0.f,0.f};
      acc = MFMA(h0, wb[t][0], acc);
      acc = MFMA(h1, wb[t][1], acc);
      #pragma unroll
      for(int r=0;r<4;r++){
        float y = acc[r];
        LT[(q*4+r)*264 + ct*16 + c] = f2bf(y / (1.f + __expf(-y)));
      }
    }
  }
  __syncthreads();

  // ---- Phase C: FFN2 partials over K-chunks {2w, 2w+1} for all 4 ct -> LP[w] ----
  {
    s8v a0 = *reinterpret_cast<const s8v*>(LT + c*264 + (2*w)*32 + q*8);
    s8v a1 = *reinterpret_cast<const s8v*>(LT + c*264 + (2*w+1)*32 + q*8);
    s8v wb[4][2];
    #pragma unroll
    for(int ct=0;ct<4;ct++){
      wb[ct][0] = *reinterpret_cast<const s8v*>(W2T + (ct*16+c)*256 + (2*w)*32 + q*8);
      wb[ct][1] = *reinterpret_cast<const s8v*>(W2T + (ct*16+c)*256 + (2*w+1)*32 + q*8);
    }
    #pragma unroll
    for(int ct=0;ct<4;ct++){
      f32x4 acc = {0.f,0.f,0.f,0.f};
      acc = MFMA(a0, wb[ct][0], acc);
      acc = MFMA(a1, wb[ct][1], acc);
      #pragma unroll
      for(int r=0;r<4;r++)
        LP[w*1088 + (q*4+r)*68 + ct*16 + c] = acc[r];
    }
  }
  __syncthreads();

  // ---- Phase D: combine + residual (cols ct=w); cross-wave LN -> hbf_out, LH ----
  float ny[4];
  #pragma unroll
  for(int r=0;r<4;r++){
    int o = (q*4+r)*68 + w*16 + c;
    size_t idx = (size_t)(row0+q*4+r)*64 + w*16 + c;
    float t = x[idx] + LP[o] + LP[1088+o] + LP[2176+o] + LP[3264+o];
    x[idx] = t;
    ny[r] = t;
    if(writex) xbf[idx] = f2bf(t);
  }
  #pragma unroll
  for(int r=0;r<4;r++){
    float s = ny[r];
    QREDUCE16(s);
    if(c == 0) LSUM[w*16 + q*4 + r] = s;
  }
  __syncthreads();
  float m2[4];
  #pragma unroll
  for(int r=0;r<4;r++)
    m2[r] = (LSUM[q*4+r] + LSUM[16+q*4+r] + LSUM[32+q*4+r] + LSUM[48+q*4+r]) * (1.f/64.f);
  #pragma unroll
  for(int r=0;r<4;r++){
    float d = ny[r]-m2[r];
    float vv = d*d;
    QREDUCE16(vv);
    if(c == 0) LSSQ[w*16 + q*4 + r] = vv;
  }
  __syncthreads();
  #pragma unroll
  for(int r=0;r<4;r++){
    float vv = LSSQ[q*4+r] + LSSQ[16+q*4+r] + LSSQ[32+q*4+r] + LSSQ[48+q*4+r];
    float rs = rsqrtf(vv*(1.f/64.f) + 1e-6f);
    u16 hb = f2bf((ny[r]-m2[r])*rs);
    hbf_out[(size_t)(row0+q*4+r)*64 + w*16 + c] = hb;
    LH[(q*4+r)*72 + w*16 + c] = hb;
  }

  // ---- Phase E: Q-proj for next layer (cols ct=w) ----
  if(haveQ){
    __syncthreads();
    s8v h0 = *reinterpret_cast<const s8v*>(LH + c*72 + q*8);
    s8v h1 = *reinterpret_cast<const s8v*>(LH + c*72 + 32 + q*8);
    s8v b0 = *reinterpret_cast<const s8v*>(WqTn + (w*16+c)*64 + q*8);
    s8v b1 = *reinterpret_cast<const s8v*>(WqTn + (w*16+c)*64 + 32 + q*8);
    f32x4 acc = {0.f,0.f,0.f,0.f};
    acc = MFMA(h0, b0, acc);
    acc = MFMA(h1, b1, acc);
    #pragma unroll
    for(int r=0;r<4;r++) Qt_out[(size_t)(row0+q*4+r)*64 + c*4 + w] = acc[r];
  }
}

// ---------------- TAIL (cooperative): 4 waves per 16-row tile, grid = N/16 ----------------
__global__ __launch_bounds__(256,4) void k_tail(const u16* xbf, const u16* WfT,
    const u16* hW1T, const float* hb1, const u16* hW2T, const float* hb2,
    const float* hW3, const float* hb3, float* energy, int M){
  __shared__ u16 LF[16*522];       // normalized feat, row stride 522
  __shared__ float LP[4*1088];     // per-wave y1 partials, row stride 68
  __shared__ float LSUM[64];       // per-wave row sums
  __shared__ float LSSQ[64];       // per-wave row sumsq
  __shared__ u16 LH[16*72];        // hh1
  int w = threadIdx.x >> 6;
  int lane = threadIdx.x & 63;
  int row0 = blockIdx.x * 16; if(row0 >= M) return;
  int c = lane & 15, q = lane >> 4;

  // ---- Phase 1: this wave computes cols [w*128, w*128+128) ----
  float fa[8][4];
  {
    s8v a0 = *reinterpret_cast<const s8v*>(xbf + (size_t)(row0+c)*64 + q*8);
    s8v a1 = *reinterpret_cast<const s8v*>(xbf + (size_t)(row0+c)*64 + 32 + q*8);
    s8v wb[8][2];
    #pragma unroll
    for(int t=0; t<8; t++){
      int ct = w*8 + t;
      wb[t][0] = *reinterpret_cast<const s8v*>(WfT + (ct*16+c)*64 + q*8);
      wb[t][1] = *reinterpret_cast<const s8v*>(WfT + (ct*16+c)*64 + 32 + q*8);
    }
    #pragma unroll
    for(int t=0; t<8; t++){
      f32x4 acc = {0.f,0.f,0.f,0.f};
      acc = MFMA(a0, wb[t][0], acc);
      acc = MFMA(a1, wb[t][1], acc);
      #pragma unroll
      for(int r=0;r<4;r++) fa[t][r] = acc[r];
    }
  }
  #pragma unroll
  for(int r=0;r<4;r++){
    float s = 0.f;
    #pragma unroll
    for(int t=0;t<8;t++) s += fa[t][r];
    QREDUCE16(s);
    if(c == 0) LSUM[w*16 + q*4 + r] = s;
  }
  __syncthreads();
  float m[4];
  #pragma unroll
  for(int r=0;r<4;r++)
    m[r] = (LSUM[q*4+r] + LSUM[16+q*4+r] + LSUM[32+q*4+r] + LSUM[48+q*4+r]) * (1.f/512.f);
  #pragma unroll
  for(int r=0;r<4;r++){
    float vv = 0.f;
    #pragma unroll
    for(int t=0;t<8;t++){ float d = fa[t][r]-m[r]; vv += d*d; }
    QREDUCE16(vv);
    if(c == 0) LSSQ[w*16 + q*4 + r] = vv;
  }
  __syncthreads();
  float rs[4];
  #pragma unroll
  for(int r=0;r<4;r++){
    float vv = LSSQ[q*4+r] + LSSQ[16+q*4+r] + LSSQ[32+q*4+r] + LSSQ[48+q*4+r];
    rs[r] = rsqrtf(vv*(1.f/512.f) + 1e-6f);
  }
  #pragma unroll
  for(int t=0;t<8;t++){
    int ct = w*8 + t;
    #pragma unroll
    for(int r=0;r<4;r++)
      LF[(q*4+r)*522 + ct*16 + c] = f2bf((fa[t][r]-m[r])*rs[r]);
  }
  __syncthreads();

  // ---- Phase 2: y1 partial over K-chunk kc in [w*4, w*4+4) ----
  {
    s8v af[4];
    #pragma unroll
    for(int t=0;t<4;t++)
      af[t] = *reinterpret_cast<const s8v*>(LF + c*522 + (w*4+t)*32 + q*8);
    #pragma unroll
    for(int ct=0; ct<4; ct++){
      s8v wb[4];
      #pragma unroll
      for(int t=0;t<4;t++)
        wb[t] = *reinterpret_cast<const s8v*>(hW1T + (size_t)(ct*16+c)*512 + (w*4+t)*32 + q*8);
      f32x4 acc = {0.f,0.f,0.f,0.f};
      #pragma unroll
      for(int t=0; t<4; t++) acc = MFMA(af[t], wb[t], acc);
      #pragma unroll
      for(int r=0;r<4;r++)
        LP[w*1088 + (q*4+r)*68 + ct*16 + c] = acc[r];
    }
  }
  __syncthreads();

  // ---- combine partials + bias; LN64 + relu -> LH (all waves redundantly) ----
  {
    float y[4][4];
    #pragma unroll
    for(int ct=0; ct<4; ct++){
      float bi = hb1[ct*16+c];
      #pragma unroll
      for(int r=0;r<4;r++){
        int o = (q*4+r)*68 + ct*16 + c;
        y[ct][r] = LP[o] + LP[1088+o] + LP[2176+o] + LP[3264+o] + bi;
      }
    }
    #pragma unroll
    for(int r=0;r<4;r++){
      float s = y[0][r]+y[1][r]+y[2][r]+y[3][r];
      QREDUCE16(s);
      float mm = s*(1.f/64.f);
      float vv = 0.f;
      #pragma unroll
      for(int ct=0;ct<4;ct++){ float d = y[ct][r]-mm; vv += d*d; }
      QREDUCE16(vv);
      float rr = rsqrtf(vv*(1.f/64.f) + 1e-6f);
      #pragma unroll
      for(int ct=0;ct<4;ct++)
        LH[(q*4+r)*72 + ct*16 + c] = f2bf(fmaxf((y[ct][r]-mm)*rr, 0.f));
    }
  }

  // ---- Phase 3: y2 = hh1 @ hW2 + b2; LN + relu; dot hW3; store energy (wave 0) ----
  {
    s8v a0 = *reinterpret_cast<const s8v*>(LH + c*72 + q*8);
    s8v a1 = *reinterpret_cast<const s8v*>(LH + c*72 + 32 + q*8);
    float y[4][4];
    s8v wb[4][2];
    #pragma unroll
    for(int ct=0; ct<4; ct++){
      wb[ct][0] = *reinterpret_cast<const s8v*>(hW2T + (ct*16+c)*64 + q*8);
      wb[ct][1] = *reinterpret_cast<const s8v*>(hW2T + (ct*16+c)*64 + 32 + q*8);
    }
    #pragma unroll
    for(int ct=0; ct<4; ct++){
      f32x4 acc = {0.f,0.f,0.f,0.f};
      acc = MFMA(a0, wb[ct][0], acc);
      acc = MFMA(a1, wb[ct][1], acc);
      float bi = hb2[ct*16+c];
      #pragma unroll
      for(int r=0;r<4;r++) y[ct][r] = acc[r] + bi;
    }
    float w3[4];
    #pragma unroll
    for(int ct=0;ct<4;ct++) w3[ct] = hW3[ct*16+c];
    float ep[4];
    #pragma unroll
    for(int r=0;r<4;r++){
      float s = y[0][r]+y[1][r]+y[2][r]+y[3][r];
      QREDUCE16(s);
      float mm = s*(1.f/64.f);
      float vv = 0.f;
      #pragma unroll
      for(int ct=0;ct<4;ct++){ float d = y[ct][r]-mm; vv += d*d; }
      QREDUCE16(vv);
      float rr = rsqrtf(vv*(1.f/64.f) + 1e-6f);
      float e = 0.f;
      #pragma unroll
      for(int ct=0;ct<4;ct++) e += fmaxf((y[ct][r]-mm)*rr, 0.f) * w3[ct];
      QREDUCE16(e);
      ep[r] = e;
    }
    if(w == 0 && c < 4){
      float ev = (c==0)?ep[0]:(c==1)?ep[1]:(c==2)?ep[2]:ep[3];
      int row = row0 + q*4 + c;
      energy[row] = ev + hb3[0];
    }
  }
}

// ---------------- POOL: one block per batch bucket; binary-search bounds in sorted batch ----------------
__global__ __launch_bounds__(256) void k_pool(const float* energy, const int* batch, float* out, int N){
  int g = blockIdx.x;
  int tid = threadIdx.x;
  int lo = 0, hi = N;
  while(lo < hi){ int mid = (lo+hi)>>1; if(batch[mid] < g) lo = mid+1; else hi = mid; }
  int s0 = lo;
  lo = 0; hi = N;
  while(lo < hi){ int mid = (lo+hi)>>1; if(batch[mid] <= g) lo = mid+1; else hi = mid; }
  int s1 = lo;
  float s = 0.f;
  for(int p = s0 + tid; p < s1; p += 256) s += energy[p];
  WREDUCE64(s);
  __shared__ float ws[4];
  int w = tid >> 6, lane = tid & 63;
  if(lane == 0) ws[w] = s;
  __syncthreads();
  if(tid == 0) out[g] = (ws[0]+ws[1]+ws[2]+ws[3]) * 0.11785113019775793f; // 1/sqrt(72)
}

extern "C" void kernel_launch(void* const* d_in, const int* in_sizes, int n_in,
                              void* d_out, int out_size, void* d_ws, size_t ws_size,
                              hipStream_t stream){
  const int*   edge_src  = (const int*)d_in[1];
  const int*   edge_dst  = (const int*)d_in[2];
  const float* edge_vec  = (const float*)d_in[3];
  const int*   batch     = (const int*)d_in[4];
  const int*   node_atom = (const int*)d_in[5];
  const float* ele    = (const float*)d_in[6];
  const float* W_embed= (const float*)d_in[7];
  const float* W_edge = (const float*)d_in[8];
  const float* Wq = (const float*)d_in[9];
  const float* Wk = (const float*)d_in[10];
  const float* Wv = (const float*)d_in[11];
  const float* Wr1= (const float*)d_in[12];
  const float* Wr2= (const float*)d_in[13];
  const float* Wo = (const float*)d_in[14];
  const float* W1 = (const float*)d_in[15];
  const float* W2 = (const float*)d_in[16];
  const float* W_feat=(const float*)d_in[17];
  const float* hW1= (const float*)d_in[18];
  const float* hb1= (const float*)d_in[19];
  const float* hW2= (const float*)d_in[20];
  const float* hb2= (const float*)d_in[21];
  const float* hW3= (const float*)d_in[22];
  const float* hb3= (const float*)d_in[23];
  (void)n_in; (void)ws_size;

  const int E = in_sizes[1];
  const int N = in_sizes[4];
  const int G = out_size;

  // ---- workspace layout ----
  char* base = (char*)d_ws;
  size_t off = 0;
  #define ALLOC(ty, name, count) ty* name = (ty*)(base + off); off = (off + (size_t)(count)*sizeof(ty) + 255) & ~(size_t)255;
  ALLOC(float, r2,    E)
  ALLOC(int,   src2,  E)
  ALLOC(int,   dst2,  E)
  ALLOC(u16,   ebf,   (size_t)E*64)
  ALLOC(float, exb,   (size_t)E*4)
  ALLOC(float, radtab,(size_t)6*RGROWS*4)
  ALLOC(u16,   hbfA,  (size_t)N*64)
  ALLOC(u16,   hbfB,  (size_t)N*64)
  ALLOC(u16,   xbf,   (size_t)N*64)
  ALLOC(float, Qt,    (size_t)N*64)
  ALLOC(float, xb,    (size_t)N*64)
  ALLOC(int,   deg,   N)
  ALLOC(int,   rowptr,N+1)
  ALLOC(int,   cursor,N)
  ALLOC(int,   csr,   E)
  ALLOC(float, energy,N)
  // contiguous prep-region
  ALLOC(u16, ele_bf, 120*32)
  ALLOC(u16, WembT, 64*32)
  ALLOC(u16, WedgeT,64*160)
  ALLOC(u16, WqT,  6*64*64)
  ALLOC(u16, WkT,  6*64*64)
  ALLOC(u16, WvT,  6*64*64)
  ALLOC(u16, Wr1T, 6*64*64)
  ALLOC(u16, WoT,  6*64*64)
  ALLOC(u16, W1T,  6*256*64)
  ALLOC(u16, W2T,  6*64*256)
  ALLOC(u16, WfT,  512*64)
  ALLOC(u16, hW1T, 64*512)
  ALLOC(u16, hW2T, 64*64)
  #undef ALLOC

  auto cdiv = [](int a, int b){ return (a + b - 1)/b; };

  k_prep<<<cdiv(405248,256),256,0,stream>>>(ele, W_embed, W_edge, Wq, Wk, Wv, Wr1, Wo,
                                            W1, W2, W_feat, hW1, hW2, ele_bf);

  hipMemsetAsync(deg, 0, (size_t)N*sizeof(int), stream);

  k_count<<<cdiv(E,256),256,0,stream>>>(edge_dst, deg, E);
  k_scan<<<1,1024,0,stream>>>(deg, rowptr, cursor, N);
  k_scatter<<<cdiv(E,256),256,0,stream>>>(edge_dst, cursor, csr, E);
  k_edge_embed<<<E/128, 256, 0, stream>>>(csr, edge_src, edge_dst, node_atom, ele_bf, edge_vec,
                                          WedgeT, ebf, r2, src2, dst2, E);
  k_radtab<<<dim3(cdiv(RGROWS*4,256),6),256,0,stream>>>(Wr1T, Wr2, radtab);
  k_pre<<<N/64,256,0,stream>>>(node_atom, ele_bf, WembT, WqT, xb, hbfA, Qt, N);

  for(int l=0; l<6; l++){
    const u16* hin  = (l&1) ? hbfB : hbfA;
    u16*       hout = (l&1) ? hbfA : hbfB;
    k_layer<<<N/16,256,0,stream>>>(rowptr, src2, dst2, hin, ebf, Qt, r2,
                                   radtab + (size_t)l*RGROWS*4,
                                   WkT + l*4096, WvT + l*4096, WoT + l*4096, xb,
                                   W1T + l*16384, W2T + l*16384,
                                   WqT + ((l<5)?(l+1):0)*4096,
                                   Qt, hout, xbf, exb,
                                   (l==5)?1:0, (l<5)?1:0, N);
  }

  k_tail<<<N/16,256,0,stream>>>(xbf, WfT, hW1T, hb1, hW2T, hb2, hW3, hb3, energy, N);
  k_pool<<<G,256,0,stream>>>(energy, batch, (float*)d_out, N);
}

// Round 12
// 565.164 us; speedup vs baseline: 1.0420x; 1.0420x over previous
//
#include <hip/hip_runtime.h>

typedef short s8v __attribute__((ext_vector_type(8)));
typedef float f32x4 __attribute__((ext_vector_type(4)));
typedef unsigned short u16;

__device__ __forceinline__ float bf2f(u16 h){
  union { unsigned u; float f; } v; v.u = ((unsigned)h) << 16; return v.f;
}
__device__ __forceinline__ u16 f2bf(float f){
  union { float f; unsigned u; } v; v.f = f;
  unsigned u = v.u;
  return (u16)((u + 0x7fffu + ((u >> 16) & 1u)) >> 16);
}
#define MFMA(a,b,c) __builtin_amdgcn_mfma_f32_16x16x32_bf16((a),(b),(c),0,0,0)

#define WREDUCE64(s) { s += __shfl_xor(s,1); s += __shfl_xor(s,2); s += __shfl_xor(s,4); \
                       s += __shfl_xor(s,8); s += __shfl_xor(s,16); s += __shfl_xor(s,32); }
#define QREDUCE16(s) { s += __shfl_xor(s,1); s += __shfl_xor(s,2); s += __shfl_xor(s,4); s += __shfl_xor(s,8); }

// 16-value butterfly within 16-lane quads: lane c (0..15) ends with sum-over-quad of val[c]
__device__ __forceinline__ float quad_butterfly16(float* val, int c){
  float v8[8], v4[4], v2[2];
  #pragma unroll
  for(int t=0;t<8;t++){
    float sent = (c&1) ? val[2*t] : val[2*t+1];
    float got = __shfl_xor(sent, 1);
    v8[t] = ((c&1) ? val[2*t+1] : val[2*t]) + got;
  }
  #pragma unroll
  for(int t=0;t<4;t++){
    float sent = ((c>>1)&1) ? v8[2*t] : v8[2*t+1];
    float got = __shfl_xor(sent, 2);
    v4[t] = (((c>>1)&1) ? v8[2*t+1] : v8[2*t]) + got;
  }
  #pragma unroll
  for(int t=0;t<2;t++){
    float sent = ((c>>2)&1) ? v4[2*t] : v4[2*t+1];
    float got = __shfl_xor(sent, 4);
    v2[t] = (((c>>2)&1) ? v4[2*t+1] : v4[2*t]) + got;
  }
  float sent = ((c>>3)&1) ? v2[0] : v2[1];
  float got = __shfl_xor(sent, 8);
  return (((c>>3)&1) ? v2[1] : v2[0]) + got;
}

// ---------------- ONE-SHOT prep: convert + all weight transposes (contiguous dst regions) ----------------
__global__ __launch_bounds__(256) void k_prep(const float* ele, const float* W_embed, const float* W_edge,
    const float* Wq, const float* Wk, const float* Wv, const float* Wr1, const float* Wo,
    const float* W1, const float* W2, const float* W_feat, const float* hW1, const float* hW2,
    u16* dst){
  int idx = blockIdx.x*256 + threadIdx.x;
  if(idx >= 405248) return;
  u16 v;
  if(idx < 3840){                    // ele convert
    v = f2bf(ele[idx]);
  } else if(idx < 5888){             // WembT: R=32,C=64,Rpad=32
    int l = idx - 3840;
    int cI = l >> 5, rI = l & 31;
    v = f2bf(W_embed[rI*64 + cI]);
  } else if(idx < 16128){            // WedgeT: R=137,C=64,Rpad=160
    int l = idx - 5888;
    int cI = l / 160, rI = l - cI*160;
    v = (rI < 137) ? f2bf(W_edge[rI*64 + cI]) : (u16)0;
  } else if(idx < 139008){           // Wq,Wk,Wv,Wr1,Wo: 5 x 6 x 64x64
    int l = idx - 16128;
    int which = l / 24576;
    int rem = l - which*24576;
    const float* src = (which==0)?Wq:(which==1)?Wk:(which==2)?Wv:(which==3)?Wr1:Wo;
    int b = rem >> 12;
    int r2 = rem & 4095;
    int cI = r2 >> 6, rI = r2 & 63;
    v = f2bf(src[b*4096 + rI*64 + cI]);
  } else if(idx < 237312){           // W1T: B=6,R=64,C=256,Rpad=64
    int l = idx - 139008;
    int b = l / 16384;
    int rem = l - b*16384;
    int cI = rem >> 6, rI = rem & 63;
    v = f2bf(W1[b*16384 + rI*256 + cI]);
  } else if(idx < 335616){           // W2T: B=6,R=256,C=64,Rpad=256
    int l = idx - 237312;
    int b = l / 16384;
    int rem = l - b*16384;
    int cI = rem >> 8, rI = rem & 255;
    v = f2bf(W2[b*16384 + rI*64 + cI]);
  } else if(idx < 368384){           // WfT: R=64,C=512,Rpad=64
    int l = idx - 335616;
    int cI = l >> 6, rI = l & 63;
    v = f2bf(W_feat[rI*512 + cI]);
  } else if(idx < 401152){           // hW1T: R=512,C=64,Rpad=512
    int l = idx - 368384;
    int cI = l >> 9, rI = l & 511;
    v = f2bf(hW1[rI*64 + cI]);
  } else {                           // hW2T: R=64,C=64
    int l = idx - 401152;
    int cI = l >> 6, rI = l & 63;
    v = f2bf(hW2[rI*64 + cI]);
  }
  dst[idx] = v;
}

// ---------------- CSR build ----------------
__global__ __launch_bounds__(256) void k_count(const int* dstI, int* deg, int E){
  int tid = blockIdx.x*256 + threadIdx.x;
  if(tid < E) atomicAdd(&deg[dstI[tid]], 1);
}
__global__ __launch_bounds__(1024) void k_scan(const int* deg, int* rowptr, int* cursor, int N){
  __shared__ int wsum[17];
  int tid = threadIdx.x;
  int per = (N + 1023) >> 10;
  int base = tid * per;
  int s = 0;
  for(int i=0;i<per;i++){ int idx = base+i; if(idx < N) s += deg[idx]; }
  int lane = tid & 63, wid = tid >> 6;
  int inc = s;
  for(int d=1; d<64; d<<=1){
    int t = __shfl_up(inc, d);
    if(lane >= d) inc += t;
  }
  if(lane == 63) wsum[wid+1] = inc;
  if(tid == 0) wsum[0] = 0;
  __syncthreads();
  if(tid == 0){ for(int w=1; w<=16; w++) wsum[w] += wsum[w-1]; }
  __syncthreads();
  int run = inc - s + wsum[wid];
  for(int i=0;i<per;i++){
    int idx = base + i;
    if(idx < N){ rowptr[idx] = run; cursor[idx] = run; run += deg[idx]; }
  }
  if(tid == 1023) rowptr[N] = wsum[16];
}
__global__ __launch_bounds__(256) void k_scatter(const int* dstI, int* cursor, int* csr, int E){
  int tid = blockIdx.x*256 + threadIdx.x;
  if(tid < E){
    int p = atomicAdd(&cursor[dstI[tid]], 1);
    csr[p] = tid;
  }
}

// ---------------- e = [nf_src, nf_dst, sh, rbf] @ W_edge, CSR order, TWO tiles per wave ----------------
// Output staged in wave-private LDS, flushed with coalesced 16B stores.
__global__ __launch_bounds__(256) void k_edge_embed(const int* csr, const int* srcI, const int* dstI,
    const int* atom, const u16* ele, const float* evec, const u16* Bt,
    u16* ebf, float* r2, int* src2, int* dst2, int E){
  __shared__ u16 stage[4][32*64];
  int widL = threadIdx.x >> 6;
  int wave = (blockIdx.x*256 + threadIdx.x) >> 6;
  int lane = threadIdx.x & 63;
  int base0 = wave*32; if(base0 >= E) return;
  int c = lane & 15, q = lane >> 4;
  u16* ST = stage[widL];
  s8v a[2][5];
  #pragma unroll
  for(int t=0;t<2;t++){
    int row0 = base0 + t*16;
    int p = row0 + c;
    int e = csr[p];
    int sn = srcI[e], dn = dstI[e];
    float vx = evec[(size_t)e*3+0];
    float vy = evec[(size_t)e*3+1];
    float vz = evec[(size_t)e*3+2];
    float r = sqrtf(vx*vx + vy*vy + vz*vz);
    if(q == 0){ r2[p] = r; src2[p] = sn; dst2[p] = dn; }
    float inv = 1.f/(r + 1e-12f);
    // u = edge_vec[:, [1,2,0]] / r -> x=v1, y=v2, z=v0
    float x = vy*inv, y = vz*inv, z = vx*inv;
    const float s3 = 1.7320508075688772f, s15 = 3.872983346207417f;
    const float s5h = 1.118033988749895f, s15h = 1.9364916731037085f;
    float sh[9];
    sh[0] = 1.f; sh[1] = s3*x; sh[2] = s3*y; sh[3] = s3*z;
    sh[4] = s15*x*y; sh[5] = s15*y*z; sh[6] = s5h*(3.f*z*z - 1.f);
    sh[7] = s15*x*z; sh[8] = s15h*(x*x - y*y);
    a[t][0] = *reinterpret_cast<const s8v*>(ele + (size_t)atom[sn]*32 + q*8);
    a[t][1] = *reinterpret_cast<const s8v*>(ele + (size_t)atom[dn]*32 + q*8);
    #pragma unroll
    for(int j=0;j<8;j++){
      int col = 64 + q*8 + j;
      u16 v;
      if(q == 0)            v = f2bf(sh[j]);
      else if(col < 73)     v = f2bf(sh[8]);
      else { float d = r - (10.f/63.f)*(float)(col-73); v = f2bf(__expf(-81.92f*d*d)); }
      a[t][2][j] = (short)v;
    }
    #pragma unroll
    for(int j=0;j<8;j++){
      float d = r - (10.f/63.f)*(float)(23 + q*8 + j);
      a[t][3][j] = (short)f2bf(__expf(-81.92f*d*d));
    }
    #pragma unroll
    for(int j=0;j<8;j++){
      int col = 128 + q*8 + j;
      u16 v = 0;
      if(col < 137){ float d = r - (10.f/63.f)*(float)(col-73); v = f2bf(__expf(-81.92f*d*d)); }
      a[t][4][j] = (short)v;
    }
  }
  #pragma unroll
  for(int ct=0; ct<4; ct++){
    s8v b[5];
    #pragma unroll
    for(int kc=0; kc<5; kc++)
      b[kc] = *reinterpret_cast<const s8v*>(Bt + (ct*16+c)*160 + kc*32 + q*8);
    #pragma unroll
    for(int t=0;t<2;t++){
      f32x4 acc = {0.f,0.f,0.f,0.f};
      #pragma unroll
      for(int kc=0; kc<5; kc++) acc = MFMA(a[t][kc], b[kc], acc);
      #pragma unroll
      for(int r_=0;r_<4;r_++) ST[(t*16+q*4+r_)*64 + ct*16 + c] = f2bf(acc[r_]);
    }
  }
  // coalesced flush: 32x64 u16 tile = 256 x 16B; 64 lanes x 4 iters
  #pragma unroll
  for(int k=0;k<4;k++){
    int i = k*64 + lane;
    *reinterpret_cast<float4*>(ebf + (size_t)base0*64 + (size_t)i*8) =
        *reinterpret_cast<const float4*>(ST + i*8);
  }
}

// ---------------- one-shot: radial TABLE over r-grid [0,10], 4096 intervals; layer = blockIdx.y ----------------
#define RG 4096
#define RGROWS 4112
__global__ __launch_bounds__(256) void k_radtab(const u16* Wr1T, const float* Wr2, float* radtab){
  int wave = (blockIdx.x*256 + threadIdx.x) >> 6;
  int lane = threadIdx.x & 63;
  int row0 = wave*16; if(row0 >= RGROWS) return;
  int l = blockIdx.y;
  int c = lane & 15, q = lane >> 4;
  float re = (10.f/RG)*(float)(row0 + c);
  s8v r0, r1;
  #pragma unroll
  for(int j=0;j<8;j++){
    float d0 = re - (10.f/63.f)*(float)(q*8+j);
    float d1 = re - (10.f/63.f)*(float)(32+q*8+j);
    r0[j] = (short)f2bf(__expf(-81.92f*d0*d0));
    r1[j] = (short)f2bf(__expf(-81.92f*d1*d1));
  }
  {
    const u16* W1l = Wr1T + l*4096;
    const float4* wr2v = reinterpret_cast<const float4*>(Wr2 + l*256);
    float val[16];
    #pragma unroll
    for(int i=0;i<16;i++) val[i] = 0.f;
    #pragma unroll
    for(int ct=0; ct<4; ct++){
      s8v bw0 = *reinterpret_cast<const s8v*>(W1l + (ct*16+c)*64 + q*8);
      s8v bw1 = *reinterpret_cast<const s8v*>(W1l + (ct*16+c)*64 + 32 + q*8);
      f32x4 hacc = {0.f,0.f,0.f,0.f};
      hacc = MFMA(r0, bw0, hacc); hacc = MFMA(r1, bw1, hacc);
      float4 w2 = wr2v[ct*16 + c];
      #pragma unroll
      for(int r=0;r<4;r++){
        float y = hacc[r];
        float sv = y / (1.f + __expf(-y));
        val[r*4+0] += sv * w2.x;
        val[r*4+1] += sv * w2.y;
        val[r*4+2] += sv * w2.z;
        val[r*4+3] += sv * w2.w;
      }
    }
    float fin = quad_butterfly16(val, c);
    int row = row0 + q*4 + (c>>2);
    if(row <= RG)
      radtab[(size_t)l*RGROWS*4 + (size_t)row0*4 + lane] = fin;
  }
}

// ---------------- pre: x = ele[atom]@Wemb; h0 = LN(x); Q0 = h0@Wq0 (Qt layout) ----------------
__global__ __launch_bounds__(256) void k_pre(const int* atom, const u16* ele, const u16* WembT,
    const u16* WqT0, float* xb, u16* hbf, float* Qt, int M){
  __shared__ u16 ldsH[4][16*72];
  int widL = threadIdx.x >> 6;
  int wave = (blockIdx.x*256 + threadIdx.x) >> 6;
  int lane = threadIdx.x & 63;
  int row0 = wave*16; if(row0 >= M) return;
  int c = lane & 15, q = lane >> 4;
  u16* LH = ldsH[widL];
  int at = atom[row0 + c];
  s8v a = *reinterpret_cast<const s8v*>(ele + (size_t)at*32 + q*8);
  float nx[4][4];
  #pragma unroll
  for(int ct=0; ct<4; ct++){
    s8v b = *reinterpret_cast<const s8v*>(WembT + (ct*16+c)*32 + q*8);
    f32x4 acc = {0.f,0.f,0.f,0.f};
    acc = MFMA(a, b, acc);
    #pragma unroll
    for(int r=0;r<4;r++){
      xb[(size_t)(row0+q*4+r)*64 + ct*16 + c] = acc[r];
      nx[ct][r] = acc[r];
    }
  }
  #pragma unroll
  for(int r=0;r<4;r++){
    float s = nx[0][r]+nx[1][r]+nx[2][r]+nx[3][r];
    QREDUCE16(s);
    float m = s*(1.f/64.f);
    float vv = 0.f;
    #pragma unroll
    for(int ct=0;ct<4;ct++){ float d = nx[ct][r]-m; vv += d*d; }
    QREDUCE16(vv);
    float rs = rsqrtf(vv*(1.f/64.f) + 1e-6f);
    #pragma unroll
    for(int ct=0;ct<4;ct++){
      u16 hb = f2bf((nx[ct][r]-m)*rs);
      hbf[(size_t)(row0+q*4+r)*64 + ct*16 + c] = hb;
      LH[(q*4+r)*72 + ct*16 + c] = hb;
    }
  }
  s8v h0 = *reinterpret_cast<const s8v*>(LH + c*72 + q*8);
  s8v h1 = *reinterpret_cast<const s8v*>(LH + c*72 + 32 + q*8);
  #pragma unroll
  for(int ct=0; ct<4; ct++){
    s8v b0 = *reinterpret_cast<const s8v*>(WqT0 + (ct*16+c)*64 + q*8);
    s8v b1 = *reinterpret_cast<const s8v*>(WqT0 + (ct*16+c)*64 + 32 + q*8);
    f32x4 acc = {0.f,0.f,0.f,0.f};
    acc = MFMA(h0, b0, acc);
    acc = MFMA(h1, b1, acc);
    #pragma unroll
    for(int r=0;r<4;r++) Qt[(size_t)(row0+q*4+r)*64 + c*4 + ct] = acc[r];
  }
}

// ---------------- k-only: K = (h_src+e)@Wk via MFMA linearity (no repack, no a materialization) ----------------
// qk logits + radial lerp + exp -> exb. agg uses hbf+ebf directly in k_mega.
__global__ __launch_bounds__(256,4) void k_krad(const u16* hbf, const u16* ebf,
    const int* src2, const int* dst2, const float* Qt, const float* r2, const float* radtab,
    const u16* WkT, float* exb, int E){
  int wave = (blockIdx.x*256 + threadIdx.x) >> 6;
  int lane = threadIdx.x & 63;
  int base0 = wave*32;
  if(base0 >= E) return;
  int c = lane & 15, q = lane >> 4;
  s8v h0[2], h1[2], e0[2], e1[2];
  #pragma unroll
  for(int t=0;t<2;t++){
    int row0 = base0 + t*16;
    int sr = src2[row0 + c];
    h0[t] = *reinterpret_cast<const s8v*>(hbf + (size_t)sr*64 + q*8);
    h1[t] = *reinterpret_cast<const s8v*>(hbf + (size_t)sr*64 + 32 + q*8);
    e0[t] = *reinterpret_cast<const s8v*>(ebf + (size_t)(row0+c)*64 + q*8);
    e1[t] = *reinterpret_cast<const s8v*>(ebf + (size_t)(row0+c)*64 + 32 + q*8);
  }
  // vectorized dst gather indices: dst2[base0+t*16+q*4 .. +3] contiguous
  int4 dv[2];
  #pragma unroll
  for(int t=0;t<2;t++)
    dv[t] = *reinterpret_cast<const int4*>(dst2 + base0 + t*16 + q*4);
  const float4* QtV = reinterpret_cast<const float4*>(Qt);
  float4 qv[2][4];
  #pragma unroll
  for(int t=0;t<2;t++){
    qv[t][0] = QtV[(size_t)dv[t].x*16 + c];
    qv[t][1] = QtV[(size_t)dv[t].y*16 + c];
    qv[t][2] = QtV[(size_t)dv[t].z*16 + c];
    qv[t][3] = QtV[(size_t)dv[t].w*16 + c];
  }
  // batched K-weight fragments
  s8v bk0[4], bk1[4];
  #pragma unroll
  for(int ct=0; ct<4; ct++){
    bk0[ct] = *reinterpret_cast<const s8v*>(WkT + (ct*16+c)*64 + q*8);
    bk1[ct] = *reinterpret_cast<const s8v*>(WkT + (ct*16+c)*64 + 32 + q*8);
  }
  float val[2][16];
  #pragma unroll
  for(int t=0;t<2;t++)
    #pragma unroll
    for(int i=0;i<16;i++) val[t][i] = 0.f;
  #pragma unroll
  for(int ct=0; ct<4; ct++){
    #pragma unroll
    for(int t=0;t<2;t++){
      f32x4 kacc = {0.f,0.f,0.f,0.f};
      kacc = MFMA(h0[t], bk0[ct], kacc);
      kacc = MFMA(h1[t], bk1[ct], kacc);
      kacc = MFMA(e0[t], bk0[ct], kacc);
      kacc = MFMA(e1[t], bk1[ct], kacc);
      #pragma unroll
      for(int r=0;r<4;r++){
        float qc = (ct==0)?qv[t][r].x:(ct==1)?qv[t][r].y:(ct==2)?qv[t][r].z:qv[t][r].w;
        val[t][r*4+ct] += 0.25f * kacc[r] * qc;
      }
    }
  }
  #pragma unroll
  for(int t=0;t<2;t++){
    int row0 = base0 + t*16;
    float qk = quad_butterfly16(val[t], c);   // lane c: (r=c>>2, h=c&3)
    int row = row0 + q*4 + (c>>2);
    float re = r2[row];
    float tt = re * ((float)RG/10.f);
    tt = fminf(fmaxf(tt, 0.f), (float)RG - 0.0001f);
    int i0 = (int)tt;
    float fr = tt - (float)i0;
    int h = c & 3;
    float lo = radtab[(size_t)i0*4 + h];
    float hi = radtab[(size_t)(i0+1)*4 + h];
    float logit = qk + lo + (hi - lo)*fr;
    exb[(size_t)row0*4 + lane] = (re < 10.f) ? __expf(logit) : 0.f;
  }
}

// ---------------- MEGA: per-head agg_pre = sum(alpha_h*(h_src+e)); @Wv per head; @Wo; LN; FFN; LN; Qproj ----------------
// hbf ping-pong: reads hbf_in (prev layer), writes hbf_out (next layer) -> no intra-dispatch race.
__global__ __launch_bounds__(256,4) void k_mega(const int* rowptr, const float* exb,
    const u16* hbf_in, const u16* ebf, const int* src2,
    const u16* WvT, const u16* WoT, float* x,
    const u16* W1T, const u16* W2T, const u16* WqTn, float* Qt, u16* hbf_out, u16* xbf,
    int writex, int haveQ, int M){
  __shared__ u16 LA[4*16*72];   // per-head planes: LA + h*1152 + node*72 + dim
  __shared__ u16 LA2[16*72];
  __shared__ u16 LH[16*72];
  __shared__ u16 LT[16*264];
  __shared__ float LP[4*1088];
  __shared__ float LSUM[64];
  __shared__ float LSSQ[64];
  int w = threadIdx.x >> 6;
  int lane = threadIdx.x & 63;
  int row0 = blockIdx.x * 16; if(row0 >= M) return;
  int c = lane & 15, q = lane >> 4;

  // ---- Phase 0: per-wave, per-HEAD weighted-sum of (h_src+e) rows for 4 nodes -> LA[h] ----
  {
    int ep = lane >> 4, cc = lane & 15;
    #pragma unroll
    for(int j=0;j<4;j++){
      int n = row0 + w*4 + j;
      int s0 = rowptr[n], s1 = rowptr[n+1];
      float acc[4][4];
      #pragma unroll
      for(int h=0;h<4;h++)
        #pragma unroll
        for(int k=0;k<4;k++) acc[h][k] = 0.f;
      float dd0=0.f, dd1=0.f, dd2=0.f, dd3=0.f;
      for(int p = s0 + ep; p < s1; p += 4){
        int sr = src2[p];
        ushort4 hv = *reinterpret_cast<const ushort4*>(hbf_in + (size_t)sr*64 + cc*4);
        ushort4 ev4 = *reinterpret_cast<const ushort4*>(ebf + (size_t)p*64 + cc*4);
        float4 ex = *reinterpret_cast<const float4*>(exb + (size_t)p*4);
        float d0 = bf2f(hv.x)+bf2f(ev4.x), d1 = bf2f(hv.y)+bf2f(ev4.y);
        float d2 = bf2f(hv.z)+bf2f(ev4.z), d3 = bf2f(hv.w)+bf2f(ev4.w);
        dd0 += ex.x; dd1 += ex.y; dd2 += ex.z; dd3 += ex.w;
        acc[0][0] += ex.x*d0; acc[0][1] += ex.x*d1; acc[0][2] += ex.x*d2; acc[0][3] += ex.x*d3;
        acc[1][0] += ex.y*d0; acc[1][1] += ex.y*d1; acc[1][2] += ex.y*d2; acc[1][3] += ex.y*d3;
        acc[2][0] += ex.z*d0; acc[2][1] += ex.z*d1; acc[2][2] += ex.z*d2; acc[2][3] += ex.z*d3;
        acc[3][0] += ex.w*d0; acc[3][1] += ex.w*d1; acc[3][2] += ex.w*d2; acc[3][3] += ex.w*d3;
      }
      dd0 += __shfl_xor(dd0,16); dd0 += __shfl_xor(dd0,32);
      dd1 += __shfl_xor(dd1,16); dd1 += __shfl_xor(dd1,32);
      dd2 += __shfl_xor(dd2,16); dd2 += __shfl_xor(dd2,32);
      dd3 += __shfl_xor(dd3,16); dd3 += __shfl_xor(dd3,32);
      #pragma unroll
      for(int h=0;h<4;h++)
        #pragma unroll
        for(int k=0;k<4;k++){
          acc[h][k] += __shfl_xor(acc[h][k],16);
          acc[h][k] += __shfl_xor(acc[h][k],32);
        }
      if(ep == 0){
        float inv[4];
        inv[0] = 1.f/(dd0 + 1e-9f); inv[1] = 1.f/(dd1 + 1e-9f);
        inv[2] = 1.f/(dd2 + 1e-9f); inv[3] = 1.f/(dd3 + 1e-9f);
        #pragma unroll
        for(int h=0;h<4;h++){
          ushort4 o;
          o.x = f2bf(acc[h][0]*inv[h]); o.y = f2bf(acc[h][1]*inv[h]);
          o.z = f2bf(acc[h][2]*inv[h]); o.w = f2bf(acc[h][3]*inv[h]);
          *reinterpret_cast<ushort4*>(LA + h*1152 + (w*4+j)*72 + cc*4) = o;
        }
      }
    }
  }
  __syncthreads();

  // ---- Phase A0: agg[head w cols] = agg_pre[head w] @ Wv (cols ct=w) -> LA2 ----
  {
    s8v a0 = *reinterpret_cast<const s8v*>(LA + w*1152 + c*72 + q*8);
    s8v a1 = *reinterpret_cast<const s8v*>(LA + w*1152 + c*72 + 32 + q*8);
    s8v b0 = *reinterpret_cast<const s8v*>(WvT + (w*16+c)*64 + q*8);
    s8v b1 = *reinterpret_cast<const s8v*>(WvT + (w*16+c)*64 + 32 + q*8);
    f32x4 acc = {0.f,0.f,0.f,0.f};
    acc = MFMA(a0, b0, acc);
    acc = MFMA(a1, b1, acc);
    #pragma unroll
    for(int r=0;r<4;r++)
      LA2[(q*4+r)*72 + w*16 + c] = f2bf(acc[r]);
  }
  __syncthreads();

  // ---- Phase A: x += agg @ Wo (cols ct=w); cross-wave LN -> LH ----
  float nx[4];
  {
    s8v a0 = *reinterpret_cast<const s8v*>(LA2 + c*72 + q*8);
    s8v a1 = *reinterpret_cast<const s8v*>(LA2 + c*72 + 32 + q*8);
    s8v b0 = *reinterpret_cast<const s8v*>(WoT + (w*16+c)*64 + q*8);
    s8v b1 = *reinterpret_cast<const s8v*>(WoT + (w*16+c)*64 + 32 + q*8);
    f32x4 acc = {0.f,0.f,0.f,0.f};
    acc = MFMA(a0, b0, acc);
    acc = MFMA(a1, b1, acc);
    #pragma unroll
    for(int r=0;r<4;r++){
      size_t idx = (size_t)(row0+q*4+r)*64 + w*16 + c;
      float t = x[idx] + acc[r];
      x[idx] = t;
      nx[r] = t;
    }
  }
  #pragma unroll
  for(int r=0;r<4;r++){
    float s = nx[r];
    QREDUCE16(s);
    if(c == 0) LSUM[w*16 + q*4 + r] = s;
  }
  __syncthreads();
  float m[4];
  #pragma unroll
  for(int r=0;r<4;r++)
    m[r] = (LSUM[q*4+r] + LSUM[16+q*4+r] + LSUM[32+q*4+r] + LSUM[48+q*4+r]) * (1.f/64.f);
  #pragma unroll
  for(int r=0;r<4;r++){
    float d = nx[r]-m[r];
    float vv = d*d;
    QREDUCE16(vv);
    if(c == 0) LSSQ[w*16 + q*4 + r] = vv;
  }
  __syncthreads();
  #pragma unroll
  for(int r=0;r<4;r++){
    float vv = LSSQ[q*4+r] + LSSQ[16+q*4+r] + LSSQ[32+q*4+r] + LSSQ[48+q*4+r];
    float rs = rsqrtf(vv*(1.f/64.f) + 1e-6f);
    LH[(q*4+r)*72 + w*16 + c] = f2bf((nx[r]-m[r])*rs);
  }
  __syncthreads();

  // ---- Phase B: FFN1, cols ct in [4w, 4w+4) -> LT (batched weight loads) ----
  {
    s8v h0 = *reinterpret_cast<const s8v*>(LH + c*72 + q*8);
    s8v h1 = *reinterpret_cast<const s8v*>(LH + c*72 + 32 + q*8);
    s8v wb[4][2];
    #pragma unroll
    for(int t=0;t<4;t++){
      int ct = w*4 + t;
      wb[t][0] = *reinterpret_cast<const s8v*>(W1T + (ct*16+c)*64 + q*8);
      wb[t][1] = *reinterpret_cast<const s8v*>(W1T + (ct*16+c)*64 + 32 + q*8);
    }
    #pragma unroll
    for(int t=0;t<4;t++){
      int ct = w*4 + t;
      f32x4 acc = {0.f,0.f,0.f,0.f};
      acc = MFMA(h0, wb[t][0], acc);
      acc = MFMA(h1, wb[t][1], acc);
      #pragma unroll
      for(int r=0;r<4;r++){
        float y = acc[r];
        LT[(q*4+r)*264 + ct*16 + c] = f2bf(y / (1.f + __expf(-y)));
      }
    }
  }
  __syncthreads();

  // ---- Phase C: FFN2 partials over K-chunks {2w, 2w+1} for all 4 ct -> LP[w] ----
  {
    s8v a0 = *reinterpret_cast<const s8v*>(LT + c*264 + (2*w)*32 + q*8);
    s8v a1 = *reinterpret_cast<const s8v*>(LT + c*264 + (2*w+1)*32 + q*8);
    s8v wb[4][2];
    #pragma unroll
    for(int ct=0;ct<4;ct++){
      wb[ct][0] = *reinterpret_cast<const s8v*>(W2T + (ct*16+c)*256 + (2*w)*32 + q*8);
      wb[ct][1] = *reinterpret_cast<const s8v*>(W2T + (ct*16+c)*256 + (2*w+1)*32 + q*8);
    }
    #pragma unroll
    for(int ct=0;ct<4;ct++){
      f32x4 acc = {0.f,0.f,0.f,0.f};
      acc = MFMA(a0, wb[ct][0], acc);
      acc = MFMA(a1, wb[ct][1], acc);
      #pragma unroll
      for(int r=0;r<4;r++)
        LP[w*1088 + (q*4+r)*68 + ct*16 + c] = acc[r];
    }
  }
  __syncthreads();

  // ---- Phase D: combine + residual (cols ct=w); cross-wave LN -> hbf_out, LH ----
  float ny[4];
  #pragma unroll
  for(int r=0;r<4;r++){
    int o = (q*4+r)*68 + w*16 + c;
    size_t idx = (size_t)(row0+q*4+r)*64 + w*16 + c;
    float t = x[idx] + LP[o] + LP[1088+o] + LP[2176+o] + LP[3264+o];
    x[idx] = t;
    ny[r] = t;
    if(writex) xbf[idx] = f2bf(t);
  }
  #pragma unroll
  for(int r=0;r<4;r++){
    float s = ny[r];
    QREDUCE16(s);
    if(c == 0) LSUM[w*16 + q*4 + r] = s;
  }
  __syncthreads();
  float m2[4];
  #pragma unroll
  for(int r=0;r<4;r++)
    m2[r] = (LSUM[q*4+r] + LSUM[16+q*4+r] + LSUM[32+q*4+r] + LSUM[48+q*4+r]) * (1.f/64.f);
  #pragma unroll
  for(int r=0;r<4;r++){
    float d = ny[r]-m2[r];
    float vv = d*d;
    QREDUCE16(vv);
    if(c == 0) LSSQ[w*16 + q*4 + r] = vv;
  }
  __syncthreads();
  #pragma unroll
  for(int r=0;r<4;r++){
    float vv = LSSQ[q*4+r] + LSSQ[16+q*4+r] + LSSQ[32+q*4+r] + LSSQ[48+q*4+r];
    float rs = rsqrtf(vv*(1.f/64.f) + 1e-6f);
    u16 hb = f2bf((ny[r]-m2[r])*rs);
    hbf_out[(size_t)(row0+q*4+r)*64 + w*16 + c] = hb;
    LH[(q*4+r)*72 + w*16 + c] = hb;
  }

  // ---- Phase E: Q-proj for next layer (cols ct=w) ----
  if(haveQ){
    __syncthreads();
    s8v h0 = *reinterpret_cast<const s8v*>(LH + c*72 + q*8);
    s8v h1 = *reinterpret_cast<const s8v*>(LH + c*72 + 32 + q*8);
    s8v b0 = *reinterpret_cast<const s8v*>(WqTn + (w*16+c)*64 + q*8);
    s8v b1 = *reinterpret_cast<const s8v*>(WqTn + (w*16+c)*64 + 32 + q*8);
    f32x4 acc = {0.f,0.f,0.f,0.f};
    acc = MFMA(h0, b0, acc);
    acc = MFMA(h1, b1, acc);
    #pragma unroll
    for(int r=0;r<4;r++) Qt[(size_t)(row0+q*4+r)*64 + c*4 + w] = acc[r];
  }
}

// ---------------- TAIL (cooperative): 4 waves per 16-row tile, grid = N/16 ----------------
__global__ __launch_bounds__(256,4) void k_tail(const u16* xbf, const u16* WfT,
    const u16* hW1T, const float* hb1, const u16* hW2T, const float* hb2,
    const float* hW3, const float* hb3, float* energy, int M){
  __shared__ u16 LF[16*522];       // normalized feat, row stride 522
  __shared__ float LP[4*1088];     // per-wave y1 partials, row stride 68
  __shared__ float LSUM[64];       // per-wave row sums
  __shared__ float LSSQ[64];       // per-wave row sumsq
  __shared__ u16 LH[16*72];        // hh1
  int w = threadIdx.x >> 6;
  int lane = threadIdx.x & 63;
  int row0 = blockIdx.x * 16; if(row0 >= M) return;
  int c = lane & 15, q = lane >> 4;

  // ---- Phase 1: this wave computes cols [w*128, w*128+128) ----
  float fa[8][4];
  {
    s8v a0 = *reinterpret_cast<const s8v*>(xbf + (size_t)(row0+c)*64 + q*8);
    s8v a1 = *reinterpret_cast<const s8v*>(xbf + (size_t)(row0+c)*64 + 32 + q*8);
    s8v wb[8][2];
    #pragma unroll
    for(int t=0; t<8; t++){
      int ct = w*8 + t;
      wb[t][0] = *reinterpret_cast<const s8v*>(WfT + (ct*16+c)*64 + q*8);
      wb[t][1] = *reinterpret_cast<const s8v*>(WfT + (ct*16+c)*64 + 32 + q*8);
    }
    #pragma unroll
    for(int t=0; t<8; t++){
      f32x4 acc = {0.f,0.f,0.f,0.f};
      acc = MFMA(a0, wb[t][0], acc);
      acc = MFMA(a1, wb[t][1], acc);
      #pragma unroll
      for(int r=0;r<4;r++) fa[t][r] = acc[r];
    }
  }
  #pragma unroll
  for(int r=0;r<4;r++){
    float s = 0.f;
    #pragma unroll
    for(int t=0;t<8;t++) s += fa[t][r];
    QREDUCE16(s);
    if(c == 0) LSUM[w*16 + q*4 + r] = s;
  }
  __syncthreads();
  float m[4];
  #pragma unroll
  for(int r=0;r<4;r++)
    m[r] = (LSUM[q*4+r] + LSUM[16+q*4+r] + LSUM[32+q*4+r] + LSUM[48+q*4+r]) * (1.f/512.f);
  #pragma unroll
  for(int r=0;r<4;r++){
    float vv = 0.f;
    #pragma unroll
    for(int t=0;t<8;t++){ float d = fa[t][r]-m[r]; vv += d*d; }
    QREDUCE16(vv);
    if(c == 0) LSSQ[w*16 + q*4 + r] = vv;
  }
  __syncthreads();
  float rs[4];
  #pragma unroll
  for(int r=0;r<4;r++){
    float vv = LSSQ[q*4+r] + LSSQ[16+q*4+r] + LSSQ[32+q*4+r] + LSSQ[48+q*4+r];
    rs[r] = rsqrtf(vv*(1.f/512.f) + 1e-6f);
  }
  #pragma unroll
  for(int t=0;t<8;t++){
    int ct = w*8 + t;
    #pragma unroll
    for(int r=0;r<4;r++)
      LF[(q*4+r)*522 + ct*16 + c] = f2bf((fa[t][r]-m[r])*rs[r]);
  }
  __syncthreads();

  // ---- Phase 2: y1 partial over K-chunk kc in [w*4, w*4+4) ----
  {
    s8v af[4];
    #pragma unroll
    for(int t=0;t<4;t++)
      af[t] = *reinterpret_cast<const s8v*>(LF + c*522 + (w*4+t)*32 + q*8);
    #pragma unroll
    for(int ct=0; ct<4; ct++){
      s8v wb[4];
      #pragma unroll
      for(int t=0;t<4;t++)
        wb[t] = *reinterpret_cast<const s8v*>(hW1T + (size_t)(ct*16+c)*512 + (w*4+t)*32 + q*8);
      f32x4 acc = {0.f,0.f,0.f,0.f};
      #pragma unroll
      for(int t=0; t<4; t++) acc = MFMA(af[t], wb[t], acc);
      #pragma unroll
      for(int r=0;r<4;r++)
        LP[w*1088 + (q*4+r)*68 + ct*16 + c] = acc[r];
    }
  }
  __syncthreads();

  // ---- combine partials + bias; LN64 + relu -> LH (all waves redundantly) ----
  {
    float y[4][4];
    #pragma unroll
    for(int ct=0; ct<4; ct++){
      float bi = hb1[ct*16+c];
      #pragma unroll
      for(int r=0;r<4;r++){
        int o = (q*4+r)*68 + ct*16 + c;
        y[ct][r] = LP[o] + LP[1088+o] + LP[2176+o] + LP[3264+o] + bi;
      }
    }
    #pragma unroll
    for(int r=0;r<4;r++){
      float s = y[0][r]+y[1][r]+y[2][r]+y[3][r];
      QREDUCE16(s);
      float mm = s*(1.f/64.f);
      float vv = 0.f;
      #pragma unroll
      for(int ct=0;ct<4;ct++){ float d = y[ct][r]-mm; vv += d*d; }
      QREDUCE16(vv);
      float rr = rsqrtf(vv*(1.f/64.f) + 1e-6f);
      #pragma unroll
      for(int ct=0;ct<4;ct++)
        LH[(q*4+r)*72 + ct*16 + c] = f2bf(fmaxf((y[ct][r]-mm)*rr, 0.f));
    }
  }

  // ---- Phase 3: y2 = hh1 @ hW2 + b2; LN + relu; dot hW3; store energy (wave 0) ----
  {
    s8v a0 = *reinterpret_cast<const s8v*>(LH + c*72 + q*8);
    s8v a1 = *reinterpret_cast<const s8v*>(LH + c*72 + 32 + q*8);
    float y[4][4];
    s8v wb[4][2];
    #pragma unroll
    for(int ct=0; ct<4; ct++){
      wb[ct][0] = *reinterpret_cast<const s8v*>(hW2T + (ct*16+c)*64 + q*8);
      wb[ct][1] = *reinterpret_cast<const s8v*>(hW2T + (ct*16+c)*64 + 32 + q*8);
    }
    #pragma unroll
    for(int ct=0; ct<4; ct++){
      f32x4 acc = {0.f,0.f,0.f,0.f};
      acc = MFMA(a0, wb[ct][0], acc);
      acc = MFMA(a1, wb[ct][1], acc);
      float bi = hb2[ct*16+c];
      #pragma unroll
      for(int r=0;r<4;r++) y[ct][r] = acc[r] + bi;
    }
    float w3[4];
    #pragma unroll
    for(int ct=0;ct<4;ct++) w3[ct] = hW3[ct*16+c];
    float ep[4];
    #pragma unroll
    for(int r=0;r<4;r++){
      float s = y[0][r]+y[1][r]+y[2][r]+y[3][r];
      QREDUCE16(s);
      float mm = s*(1.f/64.f);
      float vv = 0.f;
      #pragma unroll
      for(int ct=0;ct<4;ct++){ float d = y[ct][r]-mm; vv += d*d; }
      QREDUCE16(vv);
      float rr = rsqrtf(vv*(1.f/64.f) + 1e-6f);
      float e = 0.f;
      #pragma unroll
      for(int ct=0;ct<4;ct++) e += fmaxf((y[ct][r]-mm)*rr, 0.f) * w3[ct];
      QREDUCE16(e);
      ep[r] = e;
    }
    if(w == 0 && c < 4){
      float ev = (c==0)?ep[0]:(c==1)?ep[1]:(c==2)?ep[2]:ep[3];
      int row = row0 + q*4 + c;
      energy[row] = ev + hb3[0];
    }
  }
}

// ---------------- POOL: one block per batch bucket; binary-search bounds in sorted batch ----------------
__global__ __launch_bounds__(256) void k_pool(const float* energy, const int* batch, float* out, int N){
  int g = blockIdx.x;
  int tid = threadIdx.x;
  int lo = 0, hi = N;
  while(lo < hi){ int mid = (lo+hi)>>1; if(batch[mid] < g) lo = mid+1; else hi = mid; }
  int s0 = lo;
  lo = 0; hi = N;
  while(lo < hi){ int mid = (lo+hi)>>1; if(batch[mid] <= g) lo = mid+1; else hi = mid; }
  int s1 = lo;
  float s = 0.f;
  for(int p = s0 + tid; p < s1; p += 256) s += energy[p];
  WREDUCE64(s);
  __shared__ float ws[4];
  int w = tid >> 6, lane = tid & 63;
  if(lane == 0) ws[w] = s;
  __syncthreads();
  if(tid == 0) out[g] = (ws[0]+ws[1]+ws[2]+ws[3]) * 0.11785113019775793f; // 1/sqrt(72)
}

extern "C" void kernel_launch(void* const* d_in, const int* in_sizes, int n_in,
                              void* d_out, int out_size, void* d_ws, size_t ws_size,
                              hipStream_t stream){
  const int*   edge_src  = (const int*)d_in[1];
  const int*   edge_dst  = (const int*)d_in[2];
  const float* edge_vec  = (const float*)d_in[3];
  const int*   batch     = (const int*)d_in[4];
  const int*   node_atom = (const int*)d_in[5];
  const float* ele    = (const float*)d_in[6];
  const float* W_embed= (const float*)d_in[7];
  const float* W_edge = (const float*)d_in[8];
  const float* Wq = (const float*)d_in[9];
  const float* Wk = (const float*)d_in[10];
  const float* Wv = (const float*)d_in[11];
  const float* Wr1= (const float*)d_in[12];
  const float* Wr2= (const float*)d_in[13];
  const float* Wo = (const float*)d_in[14];
  const float* W1 = (const float*)d_in[15];
  const float* W2 = (const float*)d_in[16];
  const float* W_feat=(const float*)d_in[17];
  const float* hW1= (const float*)d_in[18];
  const float* hb1= (const float*)d_in[19];
  const float* hW2= (const float*)d_in[20];
  const float* hb2= (const float*)d_in[21];
  const float* hW3= (const float*)d_in[22];
  const float* hb3= (const float*)d_in[23];
  (void)n_in; (void)ws_size;

  const int E = in_sizes[1];
  const int N = in_sizes[4];
  const int G = out_size;

  // ---- workspace layout ----
  char* base = (char*)d_ws;
  size_t off = 0;
  #define ALLOC(ty, name, count) ty* name = (ty*)(base + off); off = (off + (size_t)(count)*sizeof(ty) + 255) & ~(size_t)255;
  ALLOC(float, r2,    E)
  ALLOC(int,   src2,  E)
  ALLOC(int,   dst2,  E)
  ALLOC(u16,   ebf,   (size_t)E*64)
  ALLOC(float, exb,   (size_t)E*4)
  ALLOC(float, radtab,(size_t)6*RGROWS*4)
  ALLOC(u16,   hbfA,  (size_t)N*64)
  ALLOC(u16,   hbfB,  (size_t)N*64)
  ALLOC(u16,   xbf,   (size_t)N*64)
  ALLOC(float, Qt,    (size_t)N*64)
  ALLOC(float, xb,    (size_t)N*64)
  ALLOC(int,   deg,   N)
  ALLOC(int,   rowptr,N+1)
  ALLOC(int,   cursor,N)
  ALLOC(int,   csr,   E)
  ALLOC(float, energy,N)
  // contiguous prep-region
  ALLOC(u16, ele_bf, 120*32)
  ALLOC(u16, WembT, 64*32)
  ALLOC(u16, WedgeT,64*160)
  ALLOC(u16, WqT,  6*64*64)
  ALLOC(u16, WkT,  6*64*64)
  ALLOC(u16, WvT,  6*64*64)
  ALLOC(u16, Wr1T, 6*64*64)
  ALLOC(u16, WoT,  6*64*64)
  ALLOC(u16, W1T,  6*256*64)
  ALLOC(u16, W2T,  6*64*256)
  ALLOC(u16, WfT,  512*64)
  ALLOC(u16, hW1T, 64*512)
  ALLOC(u16, hW2T, 64*64)
  #undef ALLOC

  auto cdiv = [](int a, int b){ return (a + b - 1)/b; };

  k_prep<<<cdiv(405248,256),256,0,stream>>>(ele, W_embed, W_edge, Wq, Wk, Wv, Wr1, Wo,
                                            W1, W2, W_feat, hW1, hW2, ele_bf);

  hipMemsetAsync(deg, 0, (size_t)N*sizeof(int), stream);

  k_count<<<cdiv(E,256),256,0,stream>>>(edge_dst, deg, E);
  k_scan<<<1,1024,0,stream>>>(deg, rowptr, cursor, N);
  k_scatter<<<cdiv(E,256),256,0,stream>>>(edge_dst, cursor, csr, E);
  k_edge_embed<<<E/128, 256, 0, stream>>>(csr, edge_src, edge_dst, node_atom, ele_bf, edge_vec,
                                          WedgeT, ebf, r2, src2, dst2, E);
  k_radtab<<<dim3(cdiv(RGROWS*4,256),6),256,0,stream>>>(Wr1T, Wr2, radtab);
  k_pre<<<N/64,256,0,stream>>>(node_atom, ele_bf, WembT, WqT, xb, hbfA, Qt, N);

  for(int l=0; l<6; l++){
    const u16* hin  = (l&1) ? hbfB : hbfA;
    u16*       hout = (l&1) ? hbfA : hbfB;
    k_krad<<<E/128,256,0,stream>>>(hin, ebf, src2, dst2, Qt, r2, radtab + (size_t)l*RGROWS*4,
                                   WkT + l*4096, exb, E);
    k_mega<<<N/16,256,0,stream>>>(rowptr, exb, hin, ebf, src2,
                                  WvT + l*4096, WoT + l*4096, xb,
                                  W1T + l*16384, W2T + l*16384,
                                  WqT + ((l<5)?(l+1):0)*4096, Qt, hout, xbf,
                                  (l==5)?1:0, (l<5)?1:0, N);
  }

  k_tail<<<N/16,256,0,stream>>>(xbf, WfT, hW1T, hb1, hW2T, hb2, hW3, hb3, energy, N);
  k_pool<<<G,256,0,stream>>>(energy, batch, (float*)d_out, N);
}

// Round 13
// 552.962 us; speedup vs baseline: 1.0650x; 1.0221x over previous
//
#include <hip/hip_runtime.h>

typedef short s8v __attribute__((ext_vector_type(8)));
typedef float f32x4 __attribute__((ext_vector_type(4)));
typedef unsigned short u16;

__device__ __forceinline__ float bf2f(u16 h){
  union { unsigned u; float f; } v; v.u = ((unsigned)h) << 16; return v.f;
}
__device__ __forceinline__ u16 f2bf(float f){
  union { float f; unsigned u; } v; v.f = f;
  unsigned u = v.u;
  return (u16)((u + 0x7fffu + ((u >> 16) & 1u)) >> 16);
}
#define MFMA(a,b,c) __builtin_amdgcn_mfma_f32_16x16x32_bf16((a),(b),(c),0,0,0)

#define WREDUCE64(s) { s += __shfl_xor(s,1); s += __shfl_xor(s,2); s += __shfl_xor(s,4); \
                       s += __shfl_xor(s,8); s += __shfl_xor(s,16); s += __shfl_xor(s,32); }
#define QREDUCE16(s) { s += __shfl_xor(s,1); s += __shfl_xor(s,2); s += __shfl_xor(s,4); s += __shfl_xor(s,8); }

// 16-value butterfly within 16-lane quads: lane c (0..15) ends with sum-over-quad of val[c]
__device__ __forceinline__ float quad_butterfly16(float* val, int c){
  float v8[8], v4[4], v2[2];
  #pragma unroll
  for(int t=0;t<8;t++){
    float sent = (c&1) ? val[2*t] : val[2*t+1];
    float got = __shfl_xor(sent, 1);
    v8[t] = ((c&1) ? val[2*t+1] : val[2*t]) + got;
  }
  #pragma unroll
  for(int t=0;t<4;t++){
    float sent = ((c>>1)&1) ? v8[2*t] : v8[2*t+1];
    float got = __shfl_xor(sent, 2);
    v4[t] = (((c>>1)&1) ? v8[2*t+1] : v8[2*t]) + got;
  }
  #pragma unroll
  for(int t=0;t<2;t++){
    float sent = ((c>>2)&1) ? v4[2*t] : v4[2*t+1];
    float got = __shfl_xor(sent, 4);
    v2[t] = (((c>>2)&1) ? v4[2*t+1] : v4[2*t]) + got;
  }
  float sent = ((c>>3)&1) ? v2[0] : v2[1];
  float got = __shfl_xor(sent, 8);
  return (((c>>3)&1) ? v2[1] : v2[0]) + got;
}

// ---------------- ONE-SHOT prep: convert + all weight transposes (contiguous dst regions) ----------------
__global__ __launch_bounds__(256) void k_prep(const float* ele, const float* W_embed, const float* W_edge,
    const float* Wq, const float* Wk, const float* Wv, const float* Wr1, const float* Wo,
    const float* W1, const float* W2, const float* W_feat, const float* hW1, const float* hW2,
    u16* dst){
  int idx = blockIdx.x*256 + threadIdx.x;
  if(idx >= 405248) return;
  u16 v;
  if(idx < 3840){                    // ele convert
    v = f2bf(ele[idx]);
  } else if(idx < 5888){             // WembT: R=32,C=64,Rpad=32
    int l = idx - 3840;
    int cI = l >> 5, rI = l & 31;
    v = f2bf(W_embed[rI*64 + cI]);
  } else if(idx < 16128){            // WedgeT: R=137,C=64,Rpad=160
    int l = idx - 5888;
    int cI = l / 160, rI = l - cI*160;
    v = (rI < 137) ? f2bf(W_edge[rI*64 + cI]) : (u16)0;
  } else if(idx < 139008){           // Wq,Wk,Wv,Wr1,Wo: 5 x 6 x 64x64
    int l = idx - 16128;
    int which = l / 24576;
    int rem = l - which*24576;
    const float* src = (which==0)?Wq:(which==1)?Wk:(which==2)?Wv:(which==3)?Wr1:Wo;
    int b = rem >> 12;
    int r2 = rem & 4095;
    int cI = r2 >> 6, rI = r2 & 63;
    v = f2bf(src[b*4096 + rI*64 + cI]);
  } else if(idx < 237312){           // W1T: B=6,R=64,C=256,Rpad=64
    int l = idx - 139008;
    int b = l / 16384;
    int rem = l - b*16384;
    int cI = rem >> 6, rI = rem & 63;
    v = f2bf(W1[b*16384 + rI*256 + cI]);
  } else if(idx < 335616){           // W2T: B=6,R=256,C=64,Rpad=256
    int l = idx - 237312;
    int b = l / 16384;
    int rem = l - b*16384;
    int cI = rem >> 8, rI = rem & 255;
    v = f2bf(W2[b*16384 + rI*64 + cI]);
  } else if(idx < 368384){           // WfT: R=64,C=512,Rpad=64
    int l = idx - 335616;
    int cI = l >> 6, rI = l & 63;
    v = f2bf(W_feat[rI*512 + cI]);
  } else if(idx < 401152){           // hW1T: R=512,C=64,Rpad=512
    int l = idx - 368384;
    int cI = l >> 9, rI = l & 511;
    v = f2bf(hW1[rI*64 + cI]);
  } else {                           // hW2T: R=64,C=64
    int l = idx - 401152;
    int cI = l >> 6, rI = l & 63;
    v = f2bf(hW2[rI*64 + cI]);
  }
  dst[idx] = v;
}

// ---------------- CSR build ----------------
__global__ __launch_bounds__(256) void k_count(const int* dstI, int* deg, int E){
  int tid = blockIdx.x*256 + threadIdx.x;
  if(tid < E) atomicAdd(&deg[dstI[tid]], 1);
}
__global__ __launch_bounds__(1024) void k_scan(const int* deg, int* rowptr, int* cursor, int N){
  __shared__ int wsum[17];
  int tid = threadIdx.x;
  int per = (N + 1023) >> 10;
  int base = tid * per;
  int s = 0;
  for(int i=0;i<per;i++){ int idx = base+i; if(idx < N) s += deg[idx]; }
  int lane = tid & 63, wid = tid >> 6;
  int inc = s;
  for(int d=1; d<64; d<<=1){
    int t = __shfl_up(inc, d);
    if(lane >= d) inc += t;
  }
  if(lane == 63) wsum[wid+1] = inc;
  if(tid == 0) wsum[0] = 0;
  __syncthreads();
  if(tid == 0){ for(int w=1; w<=16; w++) wsum[w] += wsum[w-1]; }
  __syncthreads();
  int run = inc - s + wsum[wid];
  for(int i=0;i<per;i++){
    int idx = base + i;
    if(idx < N){ rowptr[idx] = run; cursor[idx] = run; run += deg[idx]; }
  }
  if(tid == 1023) rowptr[N] = wsum[16];
}
__global__ __launch_bounds__(256) void k_scatter(const int* dstI, int* cursor, int* csr, int E){
  int tid = blockIdx.x*256 + threadIdx.x;
  if(tid < E){
    int p = atomicAdd(&cursor[dstI[tid]], 1);
    csr[p] = tid;
  }
}

// ---------------- e = [nf_src, nf_dst, sh, rbf] @ W_edge, CSR order, TWO tiles per wave ----------------
// Output staged in wave-private LDS, flushed with coalesced 16B stores.
__global__ __launch_bounds__(256) void k_edge_embed(const int* csr, const int* srcI, const int* dstI,
    const int* atom, const u16* ele, const float* evec, const u16* Bt,
    u16* ebf, float* r2, int* src2, int* dst2, int E){
  __shared__ u16 stage[4][32*64];
  int widL = threadIdx.x >> 6;
  int wave = (blockIdx.x*256 + threadIdx.x) >> 6;
  int lane = threadIdx.x & 63;
  int base0 = wave*32; if(base0 >= E) return;
  int c = lane & 15, q = lane >> 4;
  u16* ST = stage[widL];
  s8v a[2][5];
  #pragma unroll
  for(int t=0;t<2;t++){
    int row0 = base0 + t*16;
    int p = row0 + c;
    int e = csr[p];
    int sn = srcI[e], dn = dstI[e];
    float vx = evec[(size_t)e*3+0];
    float vy = evec[(size_t)e*3+1];
    float vz = evec[(size_t)e*3+2];
    float r = sqrtf(vx*vx + vy*vy + vz*vz);
    if(q == 0){ r2[p] = r; src2[p] = sn; dst2[p] = dn; }
    float inv = 1.f/(r + 1e-12f);
    // u = edge_vec[:, [1,2,0]] / r -> x=v1, y=v2, z=v0
    float x = vy*inv, y = vz*inv, z = vx*inv;
    const float s3 = 1.7320508075688772f, s15 = 3.872983346207417f;
    const float s5h = 1.118033988749895f, s15h = 1.9364916731037085f;
    float sh[9];
    sh[0] = 1.f; sh[1] = s3*x; sh[2] = s3*y; sh[3] = s3*z;
    sh[4] = s15*x*y; sh[5] = s15*y*z; sh[6] = s5h*(3.f*z*z - 1.f);
    sh[7] = s15*x*z; sh[8] = s15h*(x*x - y*y);
    a[t][0] = *reinterpret_cast<const s8v*>(ele + (size_t)atom[sn]*32 + q*8);
    a[t][1] = *reinterpret_cast<const s8v*>(ele + (size_t)atom[dn]*32 + q*8);
    #pragma unroll
    for(int j=0;j<8;j++){
      int col = 64 + q*8 + j;
      u16 v;
      if(q == 0)            v = f2bf(sh[j]);
      else if(col < 73)     v = f2bf(sh[8]);
      else { float d = r - (10.f/63.f)*(float)(col-73); v = f2bf(__expf(-81.92f*d*d)); }
      a[t][2][j] = (short)v;
    }
    #pragma unroll
    for(int j=0;j<8;j++){
      float d = r - (10.f/63.f)*(float)(23 + q*8 + j);
      a[t][3][j] = (short)f2bf(__expf(-81.92f*d*d));
    }
    #pragma unroll
    for(int j=0;j<8;j++){
      int col = 128 + q*8 + j;
      u16 v = 0;
      if(col < 137){ float d = r - (10.f/63.f)*(float)(col-73); v = f2bf(__expf(-81.92f*d*d)); }
      a[t][4][j] = (short)v;
    }
  }
  #pragma unroll
  for(int ct=0; ct<4; ct++){
    s8v b[5];
    #pragma unroll
    for(int kc=0; kc<5; kc++)
      b[kc] = *reinterpret_cast<const s8v*>(Bt + (ct*16+c)*160 + kc*32 + q*8);
    #pragma unroll
    for(int t=0;t<2;t++){
      f32x4 acc = {0.f,0.f,0.f,0.f};
      #pragma unroll
      for(int kc=0; kc<5; kc++) acc = MFMA(a[t][kc], b[kc], acc);
      #pragma unroll
      for(int r_=0;r_<4;r_++) ST[(t*16+q*4+r_)*64 + ct*16 + c] = f2bf(acc[r_]);
    }
  }
  // coalesced flush: 32x64 u16 tile = 256 x 16B; 64 lanes x 4 iters
  #pragma unroll
  for(int k=0;k<4;k++){
    int i = k*64 + lane;
    *reinterpret_cast<float4*>(ebf + (size_t)base0*64 + (size_t)i*8) =
        *reinterpret_cast<const float4*>(ST + i*8);
  }
}

// ---------------- one-shot: radial TABLE over r-grid [0,10], 4096 intervals; layer = blockIdx.y ----------------
#define RG 4096
#define RGROWS 4112
__global__ __launch_bounds__(256) void k_radtab(const u16* Wr1T, const float* Wr2, float* radtab){
  int wave = (blockIdx.x*256 + threadIdx.x) >> 6;
  int lane = threadIdx.x & 63;
  int row0 = wave*16; if(row0 >= RGROWS) return;
  int l = blockIdx.y;
  int c = lane & 15, q = lane >> 4;
  float re = (10.f/RG)*(float)(row0 + c);
  s8v r0, r1;
  #pragma unroll
  for(int j=0;j<8;j++){
    float d0 = re - (10.f/63.f)*(float)(q*8+j);
    float d1 = re - (10.f/63.f)*(float)(32+q*8+j);
    r0[j] = (short)f2bf(__expf(-81.92f*d0*d0));
    r1[j] = (short)f2bf(__expf(-81.92f*d1*d1));
  }
  {
    const u16* W1l = Wr1T + l*4096;
    const float4* wr2v = reinterpret_cast<const float4*>(Wr2 + l*256);
    float val[16];
    #pragma unroll
    for(int i=0;i<16;i++) val[i] = 0.f;
    #pragma unroll
    for(int ct=0; ct<4; ct++){
      s8v bw0 = *reinterpret_cast<const s8v*>(W1l + (ct*16+c)*64 + q*8);
      s8v bw1 = *reinterpret_cast<const s8v*>(W1l + (ct*16+c)*64 + 32 + q*8);
      f32x4 hacc = {0.f,0.f,0.f,0.f};
      hacc = MFMA(r0, bw0, hacc); hacc = MFMA(r1, bw1, hacc);
      float4 w2 = wr2v[ct*16 + c];
      #pragma unroll
      for(int r=0;r<4;r++){
        float y = hacc[r];
        float sv = y / (1.f + __expf(-y));
        val[r*4+0] += sv * w2.x;
        val[r*4+1] += sv * w2.y;
        val[r*4+2] += sv * w2.z;
        val[r*4+3] += sv * w2.w;
      }
    }
    float fin = quad_butterfly16(val, c);
    int row = row0 + q*4 + (c>>2);
    if(row <= RG)
      radtab[(size_t)l*RGROWS*4 + (size_t)row0*4 + lane] = fin;
  }
}

// ---------------- pre: x = ele[atom]@Wemb; h0 = LN(x); Q0 = h0@Wq0 (Qt layout) ----------------
__global__ __launch_bounds__(256) void k_pre(const int* atom, const u16* ele, const u16* WembT,
    const u16* WqT0, float* xb, u16* hbf, float* Qt, int M){
  __shared__ u16 ldsH[4][16*72];
  int widL = threadIdx.x >> 6;
  int wave = (blockIdx.x*256 + threadIdx.x) >> 6;
  int lane = threadIdx.x & 63;
  int row0 = wave*16; if(row0 >= M) return;
  int c = lane & 15, q = lane >> 4;
  u16* LH = ldsH[widL];
  int at = atom[row0 + c];
  s8v a = *reinterpret_cast<const s8v*>(ele + (size_t)at*32 + q*8);
  float nx[4][4];
  #pragma unroll
  for(int ct=0; ct<4; ct++){
    s8v b = *reinterpret_cast<const s8v*>(WembT + (ct*16+c)*32 + q*8);
    f32x4 acc = {0.f,0.f,0.f,0.f};
    acc = MFMA(a, b, acc);
    #pragma unroll
    for(int r=0;r<4;r++){
      xb[(size_t)(row0+q*4+r)*64 + ct*16 + c] = acc[r];
      nx[ct][r] = acc[r];
    }
  }
  #pragma unroll
  for(int r=0;r<4;r++){
    float s = nx[0][r]+nx[1][r]+nx[2][r]+nx[3][r];
    QREDUCE16(s);
    float m = s*(1.f/64.f);
    float vv = 0.f;
    #pragma unroll
    for(int ct=0;ct<4;ct++){ float d = nx[ct][r]-m; vv += d*d; }
    QREDUCE16(vv);
    float rs = rsqrtf(vv*(1.f/64.f) + 1e-6f);
    #pragma unroll
    for(int ct=0;ct<4;ct++){
      u16 hb = f2bf((nx[ct][r]-m)*rs);
      hbf[(size_t)(row0+q*4+r)*64 + ct*16 + c] = hb;
      LH[(q*4+r)*72 + ct*16 + c] = hb;
    }
  }
  s8v h0 = *reinterpret_cast<const s8v*>(LH + c*72 + q*8);
  s8v h1 = *reinterpret_cast<const s8v*>(LH + c*72 + 32 + q*8);
  #pragma unroll
  for(int ct=0; ct<4; ct++){
    s8v b0 = *reinterpret_cast<const s8v*>(WqT0 + (ct*16+c)*64 + q*8);
    s8v b1 = *reinterpret_cast<const s8v*>(WqT0 + (ct*16+c)*64 + 32 + q*8);
    f32x4 acc = {0.f,0.f,0.f,0.f};
    acc = MFMA(h0, b0, acc);
    acc = MFMA(h1, b1, acc);
    #pragma unroll
    for(int r=0;r<4;r++) Qt[(size_t)(row0+q*4+r)*64 + c*4 + ct] = acc[r];
  }
}

// ---------------- k-only: K = (h_src+e)@Wk via MFMA linearity (no repack, no a materialization) ----------------
// qk logits + radial lerp + exp -> exb. agg uses hbf+ebf directly in k_mega.
__global__ __launch_bounds__(256,4) void k_krad(const u16* hbf, const u16* ebf,
    const int* src2, const int* dst2, const float* Qt, const float* r2, const float* radtab,
    const u16* WkT, float* exb, int E){
  int wave = (blockIdx.x*256 + threadIdx.x) >> 6;
  int lane = threadIdx.x & 63;
  int base0 = wave*32;
  if(base0 >= E) return;
  int c = lane & 15, q = lane >> 4;
  s8v h0[2], h1[2], e0[2], e1[2];
  #pragma unroll
  for(int t=0;t<2;t++){
    int row0 = base0 + t*16;
    int sr = src2[row0 + c];
    h0[t] = *reinterpret_cast<const s8v*>(hbf + (size_t)sr*64 + q*8);
    h1[t] = *reinterpret_cast<const s8v*>(hbf + (size_t)sr*64 + 32 + q*8);
    e0[t] = *reinterpret_cast<const s8v*>(ebf + (size_t)(row0+c)*64 + q*8);
    e1[t] = *reinterpret_cast<const s8v*>(ebf + (size_t)(row0+c)*64 + 32 + q*8);
  }
  int4 dv[2];
  #pragma unroll
  for(int t=0;t<2;t++)
    dv[t] = *reinterpret_cast<const int4*>(dst2 + base0 + t*16 + q*4);
  const float4* QtV = reinterpret_cast<const float4*>(Qt);
  float4 qv[2][4];
  #pragma unroll
  for(int t=0;t<2;t++){
    qv[t][0] = QtV[(size_t)dv[t].x*16 + c];
    qv[t][1] = QtV[(size_t)dv[t].y*16 + c];
    qv[t][2] = QtV[(size_t)dv[t].z*16 + c];
    qv[t][3] = QtV[(size_t)dv[t].w*16 + c];
  }
  s8v bk0[4], bk1[4];
  #pragma unroll
  for(int ct=0; ct<4; ct++){
    bk0[ct] = *reinterpret_cast<const s8v*>(WkT + (ct*16+c)*64 + q*8);
    bk1[ct] = *reinterpret_cast<const s8v*>(WkT + (ct*16+c)*64 + 32 + q*8);
  }
  float val[2][16];
  #pragma unroll
  for(int t=0;t<2;t++)
    #pragma unroll
    for(int i=0;i<16;i++) val[t][i] = 0.f;
  #pragma unroll
  for(int ct=0; ct<4; ct++){
    #pragma unroll
    for(int t=0;t<2;t++){
      f32x4 kacc = {0.f,0.f,0.f,0.f};
      kacc = MFMA(h0[t], bk0[ct], kacc);
      kacc = MFMA(h1[t], bk1[ct], kacc);
      kacc = MFMA(e0[t], bk0[ct], kacc);
      kacc = MFMA(e1[t], bk1[ct], kacc);
      #pragma unroll
      for(int r=0;r<4;r++){
        float qc = (ct==0)?qv[t][r].x:(ct==1)?qv[t][r].y:(ct==2)?qv[t][r].z:qv[t][r].w;
        val[t][r*4+ct] += 0.25f * kacc[r] * qc;
      }
    }
  }
  #pragma unroll
  for(int t=0;t<2;t++){
    int row0 = base0 + t*16;
    float qk = quad_butterfly16(val[t], c);   // lane c: (r=c>>2, h=c&3)
    int row = row0 + q*4 + (c>>2);
    float re = r2[row];
    float tt = re * ((float)RG/10.f);
    tt = fminf(fmaxf(tt, 0.f), (float)RG - 0.0001f);
    int i0 = (int)tt;
    float fr = tt - (float)i0;
    int h = c & 3;
    float lo = radtab[(size_t)i0*4 + h];
    float hi = radtab[(size_t)(i0+1)*4 + h];
    float logit = qk + lo + (hi - lo)*fr;
    exb[(size_t)row0*4 + lane] = (re < 10.f) ? __expf(logit) : 0.f;
  }
}

// ---------------- MEGA: per-head agg_pre = sum(alpha_h*(h_src+e)); @Wv per head; @Wo; LN; FFN; LN; Qproj ----------------
// Phase 0 unrolled x2 for memory-level parallelism on the src2->hbf dependent chain.
__global__ __launch_bounds__(256,4) void k_mega(const int* rowptr, const float* exb,
    const u16* hbf_in, const u16* ebf, const int* src2,
    const u16* WvT, const u16* WoT, float* x,
    const u16* W1T, const u16* W2T, const u16* WqTn, float* Qt, u16* hbf_out, u16* xbf,
    int writex, int haveQ, int M){
  __shared__ u16 LA[4*16*72];   // per-head planes: LA + h*1152 + node*72 + dim
  __shared__ u16 LA2[16*72];
  __shared__ u16 LH[16*72];
  __shared__ u16 LT[16*264];
  __shared__ float LP[4*1088];
  __shared__ float LSUM[64];
  __shared__ float LSSQ[64];
  int w = threadIdx.x >> 6;
  int lane = threadIdx.x & 63;
  int row0 = blockIdx.x * 16; if(row0 >= M) return;
  int c = lane & 15, q = lane >> 4;

  // ---- Phase 0: per-wave, per-HEAD weighted-sum of (h_src+e) rows for 4 nodes -> LA[h] ----
  {
    int ep = lane >> 4, cc = lane & 15;
    #pragma unroll
    for(int j=0;j<4;j++){
      int n = row0 + w*4 + j;
      int s0 = rowptr[n], s1 = rowptr[n+1];
      float acc[4][4];
      #pragma unroll
      for(int h=0;h<4;h++)
        #pragma unroll
        for(int k=0;k<4;k++) acc[h][k] = 0.f;
      float dd0=0.f, dd1=0.f, dd2=0.f, dd3=0.f;
      int p = s0 + ep;
      // unroll-by-2: two independent src2->hbf chains in flight
      for(; p + 4 < s1; p += 8){
        int pa = p, pb = p + 4;
        int sra = src2[pa], srb = src2[pb];
        ushort4 hva = *reinterpret_cast<const ushort4*>(hbf_in + (size_t)sra*64 + cc*4);
        ushort4 hvb = *reinterpret_cast<const ushort4*>(hbf_in + (size_t)srb*64 + cc*4);
        ushort4 eva = *reinterpret_cast<const ushort4*>(ebf + (size_t)pa*64 + cc*4);
        ushort4 evb = *reinterpret_cast<const ushort4*>(ebf + (size_t)pb*64 + cc*4);
        float4 exa = *reinterpret_cast<const float4*>(exb + (size_t)pa*4);
        float4 exc = *reinterpret_cast<const float4*>(exb + (size_t)pb*4);
        float a0 = bf2f(hva.x)+bf2f(eva.x), a1 = bf2f(hva.y)+bf2f(eva.y);
        float a2 = bf2f(hva.z)+bf2f(eva.z), a3 = bf2f(hva.w)+bf2f(eva.w);
        float b0 = bf2f(hvb.x)+bf2f(evb.x), b1 = bf2f(hvb.y)+bf2f(evb.y);
        float b2 = bf2f(hvb.z)+bf2f(evb.z), b3 = bf2f(hvb.w)+bf2f(evb.w);
        dd0 += exa.x + exc.x; dd1 += exa.y + exc.y;
        dd2 += exa.z + exc.z; dd3 += exa.w + exc.w;
        acc[0][0] += exa.x*a0 + exc.x*b0; acc[0][1] += exa.x*a1 + exc.x*b1;
        acc[0][2] += exa.x*a2 + exc.x*b2; acc[0][3] += exa.x*a3 + exc.x*b3;
        acc[1][0] += exa.y*a0 + exc.y*b0; acc[1][1] += exa.y*a1 + exc.y*b1;
        acc[1][2] += exa.y*a2 + exc.y*b2; acc[1][3] += exa.y*a3 + exc.y*b3;
        acc[2][0] += exa.z*a0 + exc.z*b0; acc[2][1] += exa.z*a1 + exc.z*b1;
        acc[2][2] += exa.z*a2 + exc.z*b2; acc[2][3] += exa.z*a3 + exc.z*b3;
        acc[3][0] += exa.w*a0 + exc.w*b0; acc[3][1] += exa.w*a1 + exc.w*b1;
        acc[3][2] += exa.w*a2 + exc.w*b2; acc[3][3] += exa.w*a3 + exc.w*b3;
      }
      for(; p < s1; p += 4){
        int sr = src2[p];
        ushort4 hv = *reinterpret_cast<const ushort4*>(hbf_in + (size_t)sr*64 + cc*4);
        ushort4 ev4 = *reinterpret_cast<const ushort4*>(ebf + (size_t)p*64 + cc*4);
        float4 ex = *reinterpret_cast<const float4*>(exb + (size_t)p*4);
        float d0 = bf2f(hv.x)+bf2f(ev4.x), d1 = bf2f(hv.y)+bf2f(ev4.y);
        float d2 = bf2f(hv.z)+bf2f(ev4.z), d3 = bf2f(hv.w)+bf2f(ev4.w);
        dd0 += ex.x; dd1 += ex.y; dd2 += ex.z; dd3 += ex.w;
        acc[0][0] += ex.x*d0; acc[0][1] += ex.x*d1; acc[0][2] += ex.x*d2; acc[0][3] += ex.x*d3;
        acc[1][0] += ex.y*d0; acc[1][1] += ex.y*d1; acc[1][2] += ex.y*d2; acc[1][3] += ex.y*d3;
        acc[2][0] += ex.z*d0; acc[2][1] += ex.z*d1; acc[2][2] += ex.z*d2; acc[2][3] += ex.z*d3;
        acc[3][0] += ex.w*d0; acc[3][1] += ex.w*d1; acc[3][2] += ex.w*d2; acc[3][3] += ex.w*d3;
      }
      dd0 += __shfl_xor(dd0,16); dd0 += __shfl_xor(dd0,32);
      dd1 += __shfl_xor(dd1,16); dd1 += __shfl_xor(dd1,32);
      dd2 += __shfl_xor(dd2,16); dd2 += __shfl_xor(dd2,32);
      dd3 += __shfl_xor(dd3,16); dd3 += __shfl_xor(dd3,32);
      #pragma unroll
      for(int h=0;h<4;h++)
        #pragma unroll
        for(int k=0;k<4;k++){
          acc[h][k] += __shfl_xor(acc[h][k],16);
          acc[h][k] += __shfl_xor(acc[h][k],32);
        }
      if(ep == 0){
        float inv[4];
        inv[0] = 1.f/(dd0 + 1e-9f); inv[1] = 1.f/(dd1 + 1e-9f);
        inv[2] = 1.f/(dd2 + 1e-9f); inv[3] = 1.f/(dd3 + 1e-9f);
        #pragma unroll
        for(int h=0;h<4;h++){
          ushort4 o;
          o.x = f2bf(acc[h][0]*inv[h]); o.y = f2bf(acc[h][1]*inv[h]);
          o.z = f2bf(acc[h][2]*inv[h]); o.w = f2bf(acc[h][3]*inv[h]);
          *reinterpret_cast<ushort4*>(LA + h*1152 + (w*4+j)*72 + cc*4) = o;
        }
      }
    }
  }
  __syncthreads();

  // ---- Phase A0: agg[head w cols] = agg_pre[head w] @ Wv (cols ct=w) -> LA2 ----
  {
    s8v a0 = *reinterpret_cast<const s8v*>(LA + w*1152 + c*72 + q*8);
    s8v a1 = *reinterpret_cast<const s8v*>(LA + w*1152 + c*72 + 32 + q*8);
    s8v b0 = *reinterpret_cast<const s8v*>(WvT + (w*16+c)*64 + q*8);
    s8v b1 = *reinterpret_cast<const s8v*>(WvT + (w*16+c)*64 + 32 + q*8);
    f32x4 acc = {0.f,0.f,0.f,0.f};
    acc = MFMA(a0, b0, acc);
    acc = MFMA(a1, b1, acc);
    #pragma unroll
    for(int r=0;r<4;r++)
      LA2[(q*4+r)*72 + w*16 + c] = f2bf(acc[r]);
  }
  __syncthreads();

  // ---- Phase A: x += agg @ Wo (cols ct=w); cross-wave LN -> LH ----
  float nx[4];
  {
    s8v a0 = *reinterpret_cast<const s8v*>(LA2 + c*72 + q*8);
    s8v a1 = *reinterpret_cast<const s8v*>(LA2 + c*72 + 32 + q*8);
    s8v b0 = *reinterpret_cast<const s8v*>(WoT + (w*16+c)*64 + q*8);
    s8v b1 = *reinterpret_cast<const s8v*>(WoT + (w*16+c)*64 + 32 + q*8);
    f32x4 acc = {0.f,0.f,0.f,0.f};
    acc = MFMA(a0, b0, acc);
    acc = MFMA(a1, b1, acc);
    #pragma unroll
    for(int r=0;r<4;r++){
      size_t idx = (size_t)(row0+q*4+r)*64 + w*16 + c;
      float t = x[idx] + acc[r];
      x[idx] = t;
      nx[r] = t;
    }
  }
  #pragma unroll
  for(int r=0;r<4;r++){
    float s = nx[r];
    QREDUCE16(s);
    if(c == 0) LSUM[w*16 + q*4 + r] = s;
  }
  __syncthreads();
  float m[4];
  #pragma unroll
  for(int r=0;r<4;r++)
    m[r] = (LSUM[q*4+r] + LSUM[16+q*4+r] + LSUM[32+q*4+r] + LSUM[48+q*4+r]) * (1.f/64.f);
  #pragma unroll
  for(int r=0;r<4;r++){
    float d = nx[r]-m[r];
    float vv = d*d;
    QREDUCE16(vv);
    if(c == 0) LSSQ[w*16 + q*4 + r] = vv;
  }
  __syncthreads();
  #pragma unroll
  for(int r=0;r<4;r++){
    float vv = LSSQ[q*4+r] + LSSQ[16+q*4+r] + LSSQ[32+q*4+r] + LSSQ[48+q*4+r];
    float rs = rsqrtf(vv*(1.f/64.f) + 1e-6f);
    LH[(q*4+r)*72 + w*16 + c] = f2bf((nx[r]-m[r])*rs);
  }
  __syncthreads();

  // ---- Phase B: FFN1, cols ct in [4w, 4w+4) -> LT (batched weight loads) ----
  {
    s8v h0 = *reinterpret_cast<const s8v*>(LH + c*72 + q*8);
    s8v h1 = *reinterpret_cast<const s8v*>(LH + c*72 + 32 + q*8);
    s8v wb[4][2];
    #pragma unroll
    for(int t=0;t<4;t++){
      int ct = w*4 + t;
      wb[t][0] = *reinterpret_cast<const s8v*>(W1T + (ct*16+c)*64 + q*8);
      wb[t][1] = *reinterpret_cast<const s8v*>(W1T + (ct*16+c)*64 + 32 + q*8);
    }
    #pragma unroll
    for(int t=0;t<4;t++){
      int ct = w*4 + t;
      f32x4 acc = {0.f,0.f,0.f,0.f};
      acc = MFMA(h0, wb[t][0], acc);
      acc = MFMA(h1, wb[t][1], acc);
      #pragma unroll
      for(int r=0;r<4;r++){
        float y = acc[r];
        LT[(q*4+r)*264 + ct*16 + c] = f2bf(y / (1.f + __expf(-y)));
      }
    }
  }
  __syncthreads();

  // ---- Phase C: FFN2 partials over K-chunks {2w, 2w+1} for all 4 ct -> LP[w] ----
  {
    s8v a0 = *reinterpret_cast<const s8v*>(LT + c*264 + (2*w)*32 + q*8);
    s8v a1 = *reinterpret_cast<const s8v*>(LT + c*264 + (2*w+1)*32 + q*8);
    s8v wb[4][2];
    #pragma unroll
    for(int ct=0;ct<4;ct++){
      wb[ct][0] = *reinterpret_cast<const s8v*>(W2T + (ct*16+c)*256 + (2*w)*32 + q*8);
      wb[ct][1] = *reinterpret_cast<const s8v*>(W2T + (ct*16+c)*256 + (2*w+1)*32 + q*8);
    }
    #pragma unroll
    for(int ct=0;ct<4;ct++){
      f32x4 acc = {0.f,0.f,0.f,0.f};
      acc = MFMA(a0, wb[ct][0], acc);
      acc = MFMA(a1, wb[ct][1], acc);
      #pragma unroll
      for(int r=0;r<4;r++)
        LP[w*1088 + (q*4+r)*68 + ct*16 + c] = acc[r];
    }
  }
  __syncthreads();

  // ---- Phase D: combine + residual (cols ct=w); cross-wave LN -> hbf_out, LH ----
  float ny[4];
  #pragma unroll
  for(int r=0;r<4;r++){
    int o = (q*4+r)*68 + w*16 + c;
    size_t idx = (size_t)(row0+q*4+r)*64 + w*16 + c;
    float t = x[idx] + LP[o] + LP[1088+o] + LP[2176+o] + LP[3264+o];
    x[idx] = t;
    ny[r] = t;
    if(writex) xbf[idx] = f2bf(t);
  }
  #pragma unroll
  for(int r=0;r<4;r++){
    float s = ny[r];
    QREDUCE16(s);
    if(c == 0) LSUM[w*16 + q*4 + r] = s;
  }
  __syncthreads();
  float m2[4];
  #pragma unroll
  for(int r=0;r<4;r++)
    m2[r] = (LSUM[q*4+r] + LSUM[16+q*4+r] + LSUM[32+q*4+r] + LSUM[48+q*4+r]) * (1.f/64.f);
  #pragma unroll
  for(int r=0;r<4;r++){
    float d = ny[r]-m2[r];
    float vv = d*d;
    QREDUCE16(vv);
    if(c == 0) LSSQ[w*16 + q*4 + r] = vv;
  }
  __syncthreads();
  #pragma unroll
  for(int r=0;r<4;r++){
    float vv = LSSQ[q*4+r] + LSSQ[16+q*4+r] + LSSQ[32+q*4+r] + LSSQ[48+q*4+r];
    float rs = rsqrtf(vv*(1.f/64.f) + 1e-6f);
    u16 hb = f2bf((ny[r]-m2[r])*rs);
    hbf_out[(size_t)(row0+q*4+r)*64 + w*16 + c] = hb;
    LH[(q*4+r)*72 + w*16 + c] = hb;
  }

  // ---- Phase E: Q-proj for next layer (cols ct=w) ----
  if(haveQ){
    __syncthreads();
    s8v h0 = *reinterpret_cast<const s8v*>(LH + c*72 + q*8);
    s8v h1 = *reinterpret_cast<const s8v*>(LH + c*72 + 32 + q*8);
    s8v b0 = *reinterpret_cast<const s8v*>(WqTn + (w*16+c)*64 + q*8);
    s8v b1 = *reinterpret_cast<const s8v*>(WqTn + (w*16+c)*64 + 32 + q*8);
    f32x4 acc = {0.f,0.f,0.f,0.f};
    acc = MFMA(h0, b0, acc);
    acc = MFMA(h1, b1, acc);
    #pragma unroll
    for(int r=0;r<4;r++) Qt[(size_t)(row0+q*4+r)*64 + c*4 + w] = acc[r];
  }
}

// ---------------- TAIL (cooperative): 4 waves per 16-row tile, grid = N/16 ----------------
__global__ __launch_bounds__(256,4) void k_tail(const u16* xbf, const u16* WfT,
    const u16* hW1T, const float* hb1, const u16* hW2T, const float* hb2,
    const float* hW3, const float* hb3, float* energy, int M){
  __shared__ u16 LF[16*522];       // normalized feat, row stride 522
  __shared__ float LP[4*1088];     // per-wave y1 partials, row stride 68
  __shared__ float LSUM[64];       // per-wave row sums
  __shared__ float LSSQ[64];       // per-wave row sumsq
  __shared__ u16 LH[16*72];        // hh1
  int w = threadIdx.x >> 6;
  int lane = threadIdx.x & 63;
  int row0 = blockIdx.x * 16; if(row0 >= M) return;
  int c = lane & 15, q = lane >> 4;

  // ---- Phase 1: this wave computes cols [w*128, w*128+128) ----
  float fa[8][4];
  {
    s8v a0 = *reinterpret_cast<const s8v*>(xbf + (size_t)(row0+c)*64 + q*8);
    s8v a1 = *reinterpret_cast<const s8v*>(xbf + (size_t)(row0+c)*64 + 32 + q*8);
    s8v wb[8][2];
    #pragma unroll
    for(int t=0; t<8; t++){
      int ct = w*8 + t;
      wb[t][0] = *reinterpret_cast<const s8v*>(WfT + (ct*16+c)*64 + q*8);
      wb[t][1] = *reinterpret_cast<const s8v*>(WfT + (ct*16+c)*64 + 32 + q*8);
    }
    #pragma unroll
    for(int t=0; t<8; t++){
      f32x4 acc = {0.f,0.f,0.f,0.f};
      acc = MFMA(a0, wb[t][0], acc);
      acc = MFMA(a1, wb[t][1], acc);
      #pragma unroll
      for(int r=0;r<4;r++) fa[t][r] = acc[r];
    }
  }
  #pragma unroll
  for(int r=0;r<4;r++){
    float s = 0.f;
    #pragma unroll
    for(int t=0;t<8;t++) s += fa[t][r];
    QREDUCE16(s);
    if(c == 0) LSUM[w*16 + q*4 + r] = s;
  }
  __syncthreads();
  float m[4];
  #pragma unroll
  for(int r=0;r<4;r++)
    m[r] = (LSUM[q*4+r] + LSUM[16+q*4+r] + LSUM[32+q*4+r] + LSUM[48+q*4+r]) * (1.f/512.f);
  #pragma unroll
  for(int r=0;r<4;r++){
    float vv = 0.f;
    #pragma unroll
    for(int t=0;t<8;t++){ float d = fa[t][r]-m[r]; vv += d*d; }
    QREDUCE16(vv);
    if(c == 0) LSSQ[w*16 + q*4 + r] = vv;
  }
  __syncthreads();
  float rs[4];
  #pragma unroll
  for(int r=0;r<4;r++){
    float vv = LSSQ[q*4+r] + LSSQ[16+q*4+r] + LSSQ[32+q*4+r] + LSSQ[48+q*4+r];
    rs[r] = rsqrtf(vv*(1.f/512.f) + 1e-6f);
  }
  #pragma unroll
  for(int t=0;t<8;t++){
    int ct = w*8 + t;
    #pragma unroll
    for(int r=0;r<4;r++)
      LF[(q*4+r)*522 + ct*16 + c] = f2bf((fa[t][r]-m[r])*rs[r]);
  }
  __syncthreads();

  // ---- Phase 2: y1 partial over K-chunk kc in [w*4, w*4+4) ----
  {
    s8v af[4];
    #pragma unroll
    for(int t=0;t<4;t++)
      af[t] = *reinterpret_cast<const s8v*>(LF + c*522 + (w*4+t)*32 + q*8);
    #pragma unroll
    for(int ct=0; ct<4; ct++){
      s8v wb[4];
      #pragma unroll
      for(int t=0;t<4;t++)
        wb[t] = *reinterpret_cast<const s8v*>(hW1T + (size_t)(ct*16+c)*512 + (w*4+t)*32 + q*8);
      f32x4 acc = {0.f,0.f,0.f,0.f};
      #pragma unroll
      for(int t=0; t<4; t++) acc = MFMA(af[t], wb[t], acc);
      #pragma unroll
      for(int r=0;r<4;r++)
        LP[w*1088 + (q*4+r)*68 + ct*16 + c] = acc[r];
    }
  }
  __syncthreads();

  // ---- combine partials + bias; LN64 + relu -> LH (all waves redundantly) ----
  {
    float y[4][4];
    #pragma unroll
    for(int ct=0; ct<4; ct++){
      float bi = hb1[ct*16+c];
      #pragma unroll
      for(int r=0;r<4;r++){
        int o = (q*4+r)*68 + ct*16 + c;
        y[ct][r] = LP[o] + LP[1088+o] + LP[2176+o] + LP[3264+o] + bi;
      }
    }
    #pragma unroll
    for(int r=0;r<4;r++){
      float s = y[0][r]+y[1][r]+y[2][r]+y[3][r];
      QREDUCE16(s);
      float mm = s*(1.f/64.f);
      float vv = 0.f;
      #pragma unroll
      for(int ct=0;ct<4;ct++){ float d = y[ct][r]-mm; vv += d*d; }
      QREDUCE16(vv);
      float rr = rsqrtf(vv*(1.f/64.f) + 1e-6f);
      #pragma unroll
      for(int ct=0;ct<4;ct++)
        LH[(q*4+r)*72 + ct*16 + c] = f2bf(fmaxf((y[ct][r]-mm)*rr, 0.f));
    }
  }

  // ---- Phase 3: y2 = hh1 @ hW2 + b2; LN + relu; dot hW3; store energy (wave 0) ----
  {
    s8v a0 = *reinterpret_cast<const s8v*>(LH + c*72 + q*8);
    s8v a1 = *reinterpret_cast<const s8v*>(LH + c*72 + 32 + q*8);
    float y[4][4];
    s8v wb[4][2];
    #pragma unroll
    for(int ct=0; ct<4; ct++){
      wb[ct][0] = *reinterpret_cast<const s8v*>(hW2T + (ct*16+c)*64 + q*8);
      wb[ct][1] = *reinterpret_cast<const s8v*>(hW2T + (ct*16+c)*64 + 32 + q*8);
    }
    #pragma unroll
    for(int ct=0; ct<4; ct++){
      f32x4 acc = {0.f,0.f,0.f,0.f};
      acc = MFMA(a0, wb[ct][0], acc);
      acc = MFMA(a1, wb[ct][1], acc);
      float bi = hb2[ct*16+c];
      #pragma unroll
      for(int r=0;r<4;r++) y[ct][r] = acc[r] + bi;
    }
    float w3[4];
    #pragma unroll
    for(int ct=0;ct<4;ct++) w3[ct] = hW3[ct*16+c];
    float ep[4];
    #pragma unroll
    for(int r=0;r<4;r++){
      float s = y[0][r]+y[1][r]+y[2][r]+y[3][r];
      QREDUCE16(s);
      float mm = s*(1.f/64.f);
      float vv = 0.f;
      #pragma unroll
      for(int ct=0;ct<4;ct++){ float d = y[ct][r]-mm; vv += d*d; }
      QREDUCE16(vv);
      float rr = rsqrtf(vv*(1.f/64.f) + 1e-6f);
      float e = 0.f;
      #pragma unroll
      for(int ct=0;ct<4;ct++) e += fmaxf((y[ct][r]-mm)*rr, 0.f) * w3[ct];
      QREDUCE16(e);
      ep[r] = e;
    }
    if(w == 0 && c < 4){
      float ev = (c==0)?ep[0]:(c==1)?ep[1]:(c==2)?ep[2]:ep[3];
      int row = row0 + q*4 + c;
      energy[row] = ev + hb3[0];
    }
  }
}

// ---------------- POOL: one block per batch bucket; binary-search bounds in sorted batch ----------------
__global__ __launch_bounds__(256) void k_pool(const float* energy, const int* batch, float* out, int N){
  int g = blockIdx.x;
  int tid = threadIdx.x;
  int lo = 0, hi = N;
  while(lo < hi){ int mid = (lo+hi)>>1; if(batch[mid] < g) lo = mid+1; else hi = mid; }
  int s0 = lo;
  lo = 0; hi = N;
  while(lo < hi){ int mid = (lo+hi)>>1; if(batch[mid] <= g) lo = mid+1; else hi = mid; }
  int s1 = lo;
  float s = 0.f;
  for(int p = s0 + tid; p < s1; p += 256) s += energy[p];
  WREDUCE64(s);
  __shared__ float ws[4];
  int w = tid >> 6, lane = tid & 63;
  if(lane == 0) ws[w] = s;
  __syncthreads();
  if(tid == 0) out[g] = (ws[0]+ws[1]+ws[2]+ws[3]) * 0.11785113019775793f; // 1/sqrt(72)
}

extern "C" void kernel_launch(void* const* d_in, const int* in_sizes, int n_in,
                              void* d_out, int out_size, void* d_ws, size_t ws_size,
                              hipStream_t stream){
  const int*   edge_src  = (const int*)d_in[1];
  const int*   edge_dst  = (const int*)d_in[2];
  const float* edge_vec  = (const float*)d_in[3];
  const int*   batch     = (const int*)d_in[4];
  const int*   node_atom = (const int*)d_in[5];
  const float* ele    = (const float*)d_in[6];
  const float* W_embed= (const float*)d_in[7];
  const float* W_edge = (const float*)d_in[8];
  const float* Wq = (const float*)d_in[9];
  const float* Wk = (const float*)d_in[10];
  const float* Wv = (const float*)d_in[11];
  const float* Wr1= (const float*)d_in[12];
  const float* Wr2= (const float*)d_in[13];
  const float* Wo = (const float*)d_in[14];
  const float* W1 = (const float*)d_in[15];
  const float* W2 = (const float*)d_in[16];
  const float* W_feat=(const float*)d_in[17];
  const float* hW1= (const float*)d_in[18];
  const float* hb1= (const float*)d_in[19];
  const float* hW2= (const float*)d_in[20];
  const float* hb2= (const float*)d_in[21];
  const float* hW3= (const float*)d_in[22];
  const float* hb3= (const float*)d_in[23];
  (void)n_in; (void)ws_size;

  const int E = in_sizes[1];
  const int N = in_sizes[4];
  const int G = out_size;

  // ---- workspace layout ----
  char* base = (char*)d_ws;
  size_t off = 0;
  #define ALLOC(ty, name, count) ty* name = (ty*)(base + off); off = (off + (size_t)(count)*sizeof(ty) + 255) & ~(size_t)255;
  ALLOC(float, r2,    E)
  ALLOC(int,   src2,  E)
  ALLOC(int,   dst2,  E)
  ALLOC(u16,   ebf,   (size_t)E*64)
  ALLOC(float, exb,   (size_t)E*4)
  ALLOC(float, radtab,(size_t)6*RGROWS*4)
  ALLOC(u16,   hbfA,  (size_t)N*64)
  ALLOC(u16,   hbfB,  (size_t)N*64)
  ALLOC(u16,   xbf,   (size_t)N*64)
  ALLOC(float, Qt,    (size_t)N*64)
  ALLOC(float, xb,    (size_t)N*64)
  ALLOC(int,   deg,   N)
  ALLOC(int,   rowptr,N+1)
  ALLOC(int,   cursor,N)
  ALLOC(int,   csr,   E)
  ALLOC(float, energy,N)
  // contiguous prep-region
  ALLOC(u16, ele_bf, 120*32)
  ALLOC(u16, WembT, 64*32)
  ALLOC(u16, WedgeT,64*160)
  ALLOC(u16, WqT,  6*64*64)
  ALLOC(u16, WkT,  6*64*64)
  ALLOC(u16, WvT,  6*64*64)
  ALLOC(u16, Wr1T, 6*64*64)
  ALLOC(u16, WoT,  6*64*64)
  ALLOC(u16, W1T,  6*256*64)
  ALLOC(u16, W2T,  6*64*256)
  ALLOC(u16, WfT,  512*64)
  ALLOC(u16, hW1T, 64*512)
  ALLOC(u16, hW2T, 64*64)
  #undef ALLOC

  auto cdiv = [](int a, int b){ return (a + b - 1)/b; };

  k_prep<<<cdiv(405248,256),256,0,stream>>>(ele, W_embed, W_edge, Wq, Wk, Wv, Wr1, Wo,
                                            W1, W2, W_feat, hW1, hW2, ele_bf);

  hipMemsetAsync(deg, 0, (size_t)N*sizeof(int), stream);

  k_count<<<cdiv(E,256),256,0,stream>>>(edge_dst, deg, E);
  k_scan<<<1,1024,0,stream>>>(deg, rowptr, cursor, N);
  k_scatter<<<cdiv(E,256),256,0,stream>>>(edge_dst, cursor, csr, E);
  k_edge_embed<<<E/128, 256, 0, stream>>>(csr, edge_src, edge_dst, node_atom, ele_bf, edge_vec,
                                          WedgeT, ebf, r2, src2, dst2, E);
  k_radtab<<<dim3(cdiv(RGROWS*4,256),6),256,0,stream>>>(Wr1T, Wr2, radtab);
  k_pre<<<N/64,256,0,stream>>>(node_atom, ele_bf, WembT, WqT, xb, hbfA, Qt, N);

  for(int l=0; l<6; l++){
    const u16* hin  = (l&1) ? hbfB : hbfA;
    u16*       hout = (l&1) ? hbfA : hbfB;
    k_krad<<<E/128,256,0,stream>>>(hin, ebf, src2, dst2, Qt, r2, radtab + (size_t)l*RGROWS*4,
                                   WkT + l*4096, exb, E);
    k_mega<<<N/16,256,0,stream>>>(rowptr, exb, hin, ebf, src2,
                                  WvT + l*4096, WoT + l*4096, xb,
                                  W1T + l*16384, W2T + l*16384,
                                  WqT + ((l<5)?(l+1):0)*4096, Qt, hout, xbf,
                                  (l==5)?1:0, (l<5)?1:0, N);
  }

  k_tail<<<N/16,256,0,stream>>>(xbf, WfT, hW1T, hb1, hW2T, hb2, hW3, hb3, energy, N);
  k_pool<<<G,256,0,stream>>>(energy, batch, (float*)d_out, N);
}